// Round 1
// baseline (703.321 us; speedup 1.0000x reference)
//
#include <hip/hip_runtime.h>
#include <hip/hip_bf16.h>
#include <math.h>

#define NDIM 512
#define NPTS 4096

typedef __attribute__((ext_vector_type(4))) float f32x4;
typedef __attribute__((ext_vector_type(8))) short short8;

__device__ __forceinline__ const float* xrow(const float* x0, const float* x1, int r){
  return (r < 256) ? (x0 + (size_t)r * NPTS) : (x1 + (size_t)(r - 256) * NPTS);
}
__device__ __forceinline__ unsigned short f2bf(float f){
  __hip_bfloat16 h = __float2bfloat16(f);
  return *reinterpret_cast<unsigned short*>(&h);
}
__device__ __forceinline__ float bf2f(unsigned short u){
  return __uint_as_float(((unsigned int)u) << 16);
}

// ---------------- row means of X (512 rows x 4096) ----------------
__global__ void k_rowmean(const float* __restrict__ x0, const float* __restrict__ x1,
                          float* __restrict__ mu){
  int r = blockIdx.x;
  const float4* row4 = (const float4*)xrow(x0, x1, r);
  float s = 0.f;
  for (int c = threadIdx.x; c < NPTS/4; c += 256){
    float4 v = row4[c];
    s += v.x + v.y + v.z + v.w;
  }
  __shared__ float red[256];
  red[threadIdx.x] = s; __syncthreads();
  for (int off = 128; off > 0; off >>= 1){
    if (threadIdx.x < off) red[threadIdx.x] += red[threadIdx.x + off];
    __syncthreads();
  }
  if (threadIdx.x == 0) mu[r] = red[0] * (1.0f / NPTS);
}

// ---------------- V = Xc Xc^T / 4095 (512x512, K=4096) ----------------
__global__ __launch_bounds__(256) void k_V(const float* __restrict__ x0, const float* __restrict__ x1,
                   const float* __restrict__ mu, float* __restrict__ V){
  __shared__ __align__(16) float As[32][68];
  __shared__ __align__(16) float Bs[32][68];
  int a0 = blockIdx.y * 32, b0 = blockIdx.x * 32;
  int t = threadIdx.x, tx = t & 15, ty = t >> 4;
  float acc00=0.f, acc01=0.f, acc10=0.f, acc11=0.f;
  for (int kb = 0; kb < NPTS; kb += 64){
    __syncthreads();
    for (int id = t; id < 512; id += 256){
      int r = id >> 4, c4 = (id & 15) * 4;
      *(float4*)&As[r][c4] = *(const float4*)(xrow(x0,x1,a0+r) + kb + c4);
      *(float4*)&Bs[r][c4] = *(const float4*)(xrow(x0,x1,b0+r) + kb + c4);
    }
    __syncthreads();
    #pragma unroll 8
    for (int kk = 0; kk < 64; kk++){
      float a0v = As[ty*2][kk],   a1v = As[ty*2+1][kk];
      float b0v = Bs[tx*2][kk],   b1v = Bs[tx*2+1][kk];
      acc00 += a0v*b0v; acc01 += a0v*b1v; acc10 += a1v*b0v; acc11 += a1v*b1v;
    }
  }
  int a = a0 + ty*2, b = b0 + tx*2;
  const float s = 1.0f/4095.0f;
  float ma = mu[a], ma1 = mu[a+1], mb = mu[b], mb1 = mu[b+1];
  V[(size_t)a*NDIM + b]       = (acc00 - (float)NPTS*ma *mb ) * s;
  V[(size_t)a*NDIM + b+1]     = (acc01 - (float)NPTS*ma *mb1) * s;
  V[(size_t)(a+1)*NDIM + b]   = (acc10 - (float)NPTS*ma1*mb ) * s;
  V[(size_t)(a+1)*NDIM + b+1] = (acc11 - (float)NPTS*ma1*mb1) * s;
}

// ---------------- 1/||V||_1 (max row abs sum) ----------------
__global__ void k_norm1(const float* __restrict__ V, float* __restrict__ rinv){
  __shared__ float red[512];
  int r = threadIdx.x;
  float s = 0.f;
  const float4* row = (const float4*)(V + (size_t)r * NDIM);
  for (int c = 0; c < NDIM/4; c++){
    float4 v = row[c];
    s += fabsf(v.x)+fabsf(v.y)+fabsf(v.z)+fabsf(v.w);
  }
  red[r] = s; __syncthreads();
  for (int off = 256; off > 0; off >>= 1){
    if (r < off) red[r] = fmaxf(red[r], red[r+off]);
    __syncthreads();
  }
  if (r == 0) rinv[0] = 1.0f / red[0];
}

__global__ void k_nsinit(const float* __restrict__ rinv, float* __restrict__ X0){
  int r = blockIdx.x;
  float c = rinv[0];
  for (int j = threadIdx.x; j < NDIM; j += 256)
    X0[(size_t)r*NDIM + j] = (j == r) ? c : 0.f;
}

// ---------------- 512^3 f32 GEMM: C = A*B   (flag: C = 2*A - A*B) ----------------
__global__ __launch_bounds__(256) void k_gemm512(const float* __restrict__ A, const float* __restrict__ B,
                                                 float* __restrict__ C, int flag){
  __shared__ __align__(16) float As[32][68];
  __shared__ __align__(16) float Bs[64][36];
  int i0 = blockIdx.y*32, j0 = blockIdx.x*32;
  int t = threadIdx.x, tx = t & 15, ty = t >> 4;
  float acc00=0.f,acc01=0.f,acc10=0.f,acc11=0.f;
  for (int kb = 0; kb < NDIM; kb += 64){
    __syncthreads();
    for (int id = t; id < 512; id += 256){
      int r = id >> 4, c4 = (id & 15)*4;
      *(float4*)&As[r][c4] = *(const float4*)(A + (size_t)(i0+r)*NDIM + kb + c4);
    }
    for (int id = t; id < 512; id += 256){
      int r = id >> 3, c4 = (id & 7)*4;
      *(float4*)&Bs[r][c4] = *(const float4*)(B + (size_t)(kb+r)*NDIM + j0 + c4);
    }
    __syncthreads();
    #pragma unroll 8
    for (int kk = 0; kk < 64; kk++){
      float av0 = As[ty*2][kk], av1 = As[ty*2+1][kk];
      float bv0 = Bs[kk][tx*2], bv1 = Bs[kk][tx*2+1];
      acc00 += av0*bv0; acc01 += av0*bv1; acc10 += av1*bv0; acc11 += av1*bv1;
    }
  }
  int i = i0 + ty*2, j = j0 + tx*2;
  if (flag){
    C[(size_t)i*NDIM+j]       = 2.f*A[(size_t)i*NDIM+j]        - acc00;
    C[(size_t)i*NDIM+j+1]     = 2.f*A[(size_t)i*NDIM+j+1]      - acc01;
    C[(size_t)(i+1)*NDIM+j]   = 2.f*A[(size_t)(i+1)*NDIM+j]    - acc10;
    C[(size_t)(i+1)*NDIM+j+1] = 2.f*A[(size_t)(i+1)*NDIM+j+1]  - acc11;
  } else {
    C[(size_t)i*NDIM+j]       = acc00;
    C[(size_t)i*NDIM+j+1]     = acc01;
    C[(size_t)(i+1)*NDIM+j]   = acc10;
    C[(size_t)(i+1)*NDIM+j+1] = acc11;
  }
}

// ---------------- Xt[i][a] = bf16(X[a][i] - mu[a])  (4096x512) ----------------
__global__ __launch_bounds__(256) void k_prepxt(const float* __restrict__ x0, const float* __restrict__ x1,
          const float* __restrict__ mu, unsigned short* __restrict__ Xt){
  __shared__ float tile[64][65];
  int i0 = blockIdx.x * 64, a0 = blockIdx.y * 64;
  int t = threadIdx.x;
  int r = t >> 2, cg = (t & 3) * 16;
  const float* row = xrow(x0, x1, a0 + r);
  #pragma unroll
  for (int e = 0; e < 16; e += 4){
    float4 v = *(const float4*)(row + i0 + cg + e);
    tile[r][cg+e] = v.x; tile[r][cg+e+1] = v.y; tile[r][cg+e+2] = v.z; tile[r][cg+e+3] = v.w;
  }
  __syncthreads();
  unsigned short outv[16] __attribute__((aligned(16)));
  #pragma unroll
  for (int e = 0; e < 16; e++){
    float v = tile[cg+e][r] - mu[a0 + cg + e];
    outv[e] = f2bf(v);
  }
  unsigned short* dst = Xt + (size_t)(i0 + r)*NDIM + a0 + cg;
  *(uint4*)dst       = *(uint4*)&outv[0];
  *(uint4*)(dst + 8) = *(uint4*)&outv[8];
}

// ---------------- Zt[i][a] = bf16( sum_b VI[a][b] * (X[b][i]-mu[b]) ) ----------------
__global__ __launch_bounds__(256) void k_gemmZ(const float* __restrict__ VI,
        const float* __restrict__ x0, const float* __restrict__ x1,
        const float* __restrict__ mu, unsigned short* __restrict__ Zt){
  __shared__ __align__(16) float As[32][68];
  __shared__ __align__(16) float Bs[64][36];
  int a0 = blockIdx.y*32, i0 = blockIdx.x*32;
  int t = threadIdx.x, tx = t & 15, ty = t >> 4;
  float acc00=0.f,acc01=0.f,acc10=0.f,acc11=0.f;
  for (int kb = 0; kb < NDIM; kb += 64){
    __syncthreads();
    for (int id = t; id < 512; id += 256){
      int r = id >> 4, c4 = (id & 15)*4;
      *(float4*)&As[r][c4] = *(const float4*)(VI + (size_t)(a0+r)*NDIM + kb + c4);
    }
    for (int id = t; id < 512; id += 256){
      int r = id >> 3, c4 = (id & 7)*4;
      float m = mu[kb + r];
      float4 v = *(const float4*)(xrow(x0,x1,kb+r) + i0 + c4);
      v.x -= m; v.y -= m; v.z -= m; v.w -= m;
      *(float4*)&Bs[r][c4] = v;
    }
    __syncthreads();
    #pragma unroll 8
    for (int kk = 0; kk < 64; kk++){
      float av0 = As[ty*2][kk], av1 = As[ty*2+1][kk];
      float bv0 = Bs[kk][tx*2], bv1 = Bs[kk][tx*2+1];
      acc00 += av0*bv0; acc01 += av0*bv1; acc10 += av1*bv0; acc11 += av1*bv1;
    }
  }
  int a = a0 + ty*2, i = i0 + tx*2;
  Zt[(size_t)i*NDIM + a]        = f2bf(acc00);
  Zt[(size_t)(i+1)*NDIM + a]    = f2bf(acc01);
  Zt[(size_t)i*NDIM + a+1]      = f2bf(acc10);
  Zt[(size_t)(i+1)*NDIM + a+1]  = f2bf(acc11);
}

// ---------------- q[i] = dot(Xt[i,:], Zt[i,:]) ----------------
__global__ void k_q(const unsigned short* __restrict__ Xt, const unsigned short* __restrict__ Zt,
                    float* __restrict__ q){
  int wave = threadIdx.x >> 6, lane = threadIdx.x & 63;
  int i = blockIdx.x * 4 + wave;
  uint4 xv = *(const uint4*)(Xt + (size_t)i*NDIM + lane*8);
  uint4 zv = *(const uint4*)(Zt + (size_t)i*NDIM + lane*8);
  const unsigned short* xs = (const unsigned short*)&xv;
  const unsigned short* zs = (const unsigned short*)&zv;
  float s = 0.f;
  #pragma unroll
  for (int e = 0; e < 8; e++) s += bf2f(xs[e]) * bf2f(zs[e]);
  #pragma unroll
  for (int off = 32; off > 0; off >>= 1) s += __shfl_down(s, off, 64);
  if (lane == 0) q[i] = s;
}

// ---------------- G tiles (bf16 MFMA) + distance epilogue ----------------
__global__ __launch_bounds__(256) void k_G(const unsigned short* __restrict__ Xt,
        const unsigned short* __restrict__ Zt, const float* __restrict__ q,
        float* __restrict__ out){
  int ti = blockIdx.x, tj = blockIdx.y;
  if (tj < ti) return;
  __shared__ __align__(16) unsigned short At[128*48];
  __shared__ __align__(16) unsigned short Bt[128*48];
  int t = threadIdx.x;
  int lane = t & 63, wave = t >> 6;
  int wr = wave >> 1, wc = wave & 1;
  f32x4 acc[4][4];
  #pragma unroll
  for (int a = 0; a < 4; a++)
    #pragma unroll
    for (int b = 0; b < 4; b++)
      acc[a][b] = (f32x4){0.f,0.f,0.f,0.f};
  int i0 = ti * 128, j0 = tj * 128;
  for (int kb = 0; kb < NDIM; kb += 32){
    __syncthreads();
    #pragma unroll
    for (int s = 0; s < 2; s++){
      int id = t + s*256;
      int r = id >> 2, c8 = (id & 3) * 8;
      *(uint4*)&At[r*48 + c8] = *(const uint4*)(Xt + (size_t)(i0+r)*NDIM + kb + c8);
      *(uint4*)&Bt[r*48 + c8] = *(const uint4*)(Zt + (size_t)(j0+r)*NDIM + kb + c8);
    }
    __syncthreads();
    short8 af[4], bfr[4];
    #pragma unroll
    for (int f = 0; f < 4; f++){
      af[f]  = *(const short8*)&At[(wr*64 + f*16 + (lane & 15))*48 + (lane >> 4)*8];
      bfr[f] = *(const short8*)&Bt[(wc*64 + f*16 + (lane & 15))*48 + (lane >> 4)*8];
    }
    #pragma unroll
    for (int fi = 0; fi < 4; fi++)
      #pragma unroll
      for (int fj = 0; fj < 4; fj++)
        acc[fi][fj] = __builtin_amdgcn_mfma_f32_16x16x32_bf16(af[fi], bfr[fj], acc[fi][fj], 0, 0, 0);
  }
  #pragma unroll
  for (int fi = 0; fi < 4; fi++){
    #pragma unroll
    for (int fj = 0; fj < 4; fj++){
      #pragma unroll
      for (int e = 0; e < 4; e++){
        int gi = i0 + wr*64 + fi*16 + (lane >> 4)*4 + e;
        int gj = j0 + wc*64 + fj*16 + (lane & 15);
        if (gi < gj){
          float d2 = q[gi] + q[gj] - 2.0f * acc[fi][fj][e];
          size_t idx = (size_t)gi * NPTS - ((size_t)gi*(gi+1))/2 + (size_t)(gj - gi - 1);
          out[idx] = sqrtf(fmaxf(d2, 1e-12f));
        }
      }
    }
  }
}

extern "C" void kernel_launch(void* const* d_in, const int* in_sizes, int n_in,
                              void* d_out, int out_size, void* d_ws, size_t ws_size,
                              hipStream_t stream) {
  (void)in_sizes; (void)n_in; (void)out_size; (void)ws_size;
  const float* x0 = (const float*)d_in[0];
  const float* x1 = (const float*)d_in[1];
  float* out = (float*)d_out;
  float* ws = (float*)d_ws;

  float* mu   = ws;                       // 512
  float* rinv = ws + 512;                 // 1 (padded to 512)
  float* V    = ws + 1024;                // 512*512
  float* N0   = V  + (size_t)NDIM*NDIM;
  float* N1   = N0 + (size_t)NDIM*NDIM;
  float* T    = N1 + (size_t)NDIM*NDIM;
  float* q    = T  + (size_t)NDIM*NDIM;   // 4096
  unsigned short* Xt = (unsigned short*)(q + NPTS);      // 4096*512 bf16
  unsigned short* Zt = Xt + (size_t)NPTS*NDIM;           // 4096*512 bf16

  k_rowmean<<<dim3(512), dim3(256), 0, stream>>>(x0, x1, mu);
  k_V<<<dim3(16,16), dim3(256), 0, stream>>>(x0, x1, mu, V);
  k_norm1<<<dim3(1), dim3(512), 0, stream>>>(V, rinv);
  k_nsinit<<<dim3(512), dim3(256), 0, stream>>>(rinv, N0);
  float* cur = N0; float* nxt = N1;
  for (int it = 0; it < 12; ++it){
    k_gemm512<<<dim3(16,16), dim3(256), 0, stream>>>(V, cur, T, 0);
    k_gemm512<<<dim3(16,16), dim3(256), 0, stream>>>(cur, T, nxt, 1);
    float* tmp = cur; cur = nxt; nxt = tmp;
  }
  k_prepxt<<<dim3(64,8), dim3(256), 0, stream>>>(x0, x1, mu, Xt);
  k_gemmZ<<<dim3(128,16), dim3(256), 0, stream>>>(cur, x0, x1, mu, Zt);
  k_q<<<dim3(1024), dim3(256), 0, stream>>>(Xt, Zt, q);
  k_G<<<dim3(32,32), dim3(256), 0, stream>>>(Xt, Zt, q, out);
}

// Round 2
// 350.187 us; speedup vs baseline: 2.0084x; 2.0084x over previous
//
#include <hip/hip_runtime.h>
#include <hip/hip_bf16.h>
#include <math.h>

#define NDIM 512
#define NPTS 4096
#define KSPLIT 4

typedef __attribute__((ext_vector_type(4))) float f32x4;
typedef __attribute__((ext_vector_type(8))) short short8;

__device__ __forceinline__ const float* xrow(const float* x0, const float* x1, int r){
  return (r < 256) ? (x0 + (size_t)r * NPTS) : (x1 + (size_t)(r - 256) * NPTS);
}
__device__ __forceinline__ unsigned short f2bf(float f){
  __hip_bfloat16 h = __float2bfloat16(f);
  return *reinterpret_cast<unsigned short*>(&h);
}
__device__ __forceinline__ float bf2f(unsigned short u){
  return __uint_as_float(((unsigned int)u) << 16);
}

// ---------------- row means of X (512 rows x 4096) ----------------
__global__ void k_rowmean(const float* __restrict__ x0, const float* __restrict__ x1,
                          float* __restrict__ mu){
  int r = blockIdx.x;
  const float4* row4 = (const float4*)xrow(x0, x1, r);
  float s = 0.f;
  for (int c = threadIdx.x; c < NPTS/4; c += 256){
    float4 v = row4[c];
    s += v.x + v.y + v.z + v.w;
  }
  __shared__ float red[256];
  red[threadIdx.x] = s; __syncthreads();
  for (int off = 128; off > 0; off >>= 1){
    if (threadIdx.x < off) red[threadIdx.x] += red[threadIdx.x + off];
    __syncthreads();
  }
  if (threadIdx.x == 0) mu[r] = red[0] * (1.0f / NPTS);
}

// ------- prep: centered X in bf16 hi/lo, both layouts (512x4096 and 4096x512) -------
__global__ __launch_bounds__(256) void k_prep(const float* __restrict__ x0, const float* __restrict__ x1,
      const float* __restrict__ mu,
      unsigned short* __restrict__ Xch, unsigned short* __restrict__ Xcl,
      unsigned short* __restrict__ Xth, unsigned short* __restrict__ Xtl){
  __shared__ float tile[64][65];
  int i0 = blockIdx.x * 64, a0 = blockIdx.y * 64;
  int t = threadIdx.x;
  int r = t >> 2, cg = (t & 3) * 16;
  const float* row = xrow(x0, x1, a0 + r);
  float m = mu[a0 + r];
  unsigned short h16[16] __attribute__((aligned(16)));
  unsigned short l16[16] __attribute__((aligned(16)));
  #pragma unroll
  for (int e = 0; e < 16; e += 4){
    float4 v = *(const float4*)(row + i0 + cg + e);
    v.x -= m; v.y -= m; v.z -= m; v.w -= m;
    tile[r][cg+e] = v.x; tile[r][cg+e+1] = v.y; tile[r][cg+e+2] = v.z; tile[r][cg+e+3] = v.w;
    h16[e]   = f2bf(v.x); l16[e]   = f2bf(v.x - bf2f(h16[e]));
    h16[e+1] = f2bf(v.y); l16[e+1] = f2bf(v.y - bf2f(h16[e+1]));
    h16[e+2] = f2bf(v.z); l16[e+2] = f2bf(v.z - bf2f(h16[e+2]));
    h16[e+3] = f2bf(v.w); l16[e+3] = f2bf(v.w - bf2f(h16[e+3]));
  }
  unsigned short* dst = Xch + (size_t)(a0+r)*NPTS + i0 + cg;
  *(uint4*)dst = *(uint4*)&h16[0]; *(uint4*)(dst+8) = *(uint4*)&h16[8];
  dst = Xcl + (size_t)(a0+r)*NPTS + i0 + cg;
  *(uint4*)dst = *(uint4*)&l16[0]; *(uint4*)(dst+8) = *(uint4*)&l16[8];
  __syncthreads();
  unsigned short th[16] __attribute__((aligned(16)));
  unsigned short tl[16] __attribute__((aligned(16)));
  #pragma unroll
  for (int e = 0; e < 16; e++){
    float v = tile[cg+e][r];
    th[e] = f2bf(v); tl[e] = f2bf(v - bf2f(th[e]));
  }
  unsigned short* d2 = Xth + (size_t)(i0 + r)*NDIM + a0 + cg;
  *(uint4*)d2 = *(uint4*)&th[0]; *(uint4*)(d2+8) = *(uint4*)&th[8];
  d2 = Xtl + (size_t)(i0 + r)*NDIM + a0 + cg;
  *(uint4*)d2 = *(uint4*)&tl[0]; *(uint4*)(d2+8) = *(uint4*)&tl[8];
}

// ------- V partials: Vp[z] = Xc(:,kz) Xc(:,kz)^T  via bf16 hi/lo MFMA (3 products) -------
__global__ __launch_bounds__(256) void k_V_mfma(const unsigned short* __restrict__ Xch,
        const unsigned short* __restrict__ Xcl, float* __restrict__ Vp){
  __shared__ __align__(16) unsigned short Ah[64*40], Al[64*40], Bh[64*40], Bl[64*40];
  int i0 = blockIdx.x*64, j0 = blockIdx.y*64;
  int t = threadIdx.x, lane = t&63, wave = t>>6;
  int wr = wave>>1, wc = wave&1;
  int lrow = lane & 15, kc = (lane>>4)*8;
  f32x4 acc[2][2];
  #pragma unroll
  for (int a = 0; a < 2; a++)
    #pragma unroll
    for (int b = 0; b < 2; b++) acc[a][b] = (f32x4){0.f,0.f,0.f,0.f};
  int r = t>>2, c8 = (t&3)*8;
  size_t kbase = (size_t)blockIdx.z * (NPTS/KSPLIT);
  const unsigned short* pAh = Xch + (size_t)(i0+r)*NPTS + kbase + c8;
  const unsigned short* pAl = Xcl + (size_t)(i0+r)*NPTS + kbase + c8;
  const unsigned short* pBh = Xch + (size_t)(j0+r)*NPTS + kbase + c8;
  const unsigned short* pBl = Xcl + (size_t)(j0+r)*NPTS + kbase + c8;
  uint4 ra_h = *(const uint4*)pAh, ra_l = *(const uint4*)pAl;
  uint4 rb_h = *(const uint4*)pBh, rb_l = *(const uint4*)pBl;
  const int NK = (NPTS/KSPLIT)/32;
  for (int kt = 0; kt < NK; kt++){
    *(uint4*)&Ah[r*40 + c8] = ra_h;
    *(uint4*)&Al[r*40 + c8] = ra_l;
    *(uint4*)&Bh[r*40 + c8] = rb_h;
    *(uint4*)&Bl[r*40 + c8] = rb_l;
    __syncthreads();
    if (kt+1 < NK){
      pAh += 32; pAl += 32; pBh += 32; pBl += 32;
      ra_h = *(const uint4*)pAh; ra_l = *(const uint4*)pAl;
      rb_h = *(const uint4*)pBh; rb_l = *(const uint4*)pBl;
    }
    short8 fah[2], fal[2], fbh[2], fbl[2];
    #pragma unroll
    for (int f = 0; f < 2; f++){
      fah[f] = *(const short8*)&Ah[(wr*32 + f*16 + lrow)*40 + kc];
      fal[f] = *(const short8*)&Al[(wr*32 + f*16 + lrow)*40 + kc];
      fbh[f] = *(const short8*)&Bh[(wc*32 + f*16 + lrow)*40 + kc];
      fbl[f] = *(const short8*)&Bl[(wc*32 + f*16 + lrow)*40 + kc];
    }
    #pragma unroll
    for (int fi = 0; fi < 2; fi++)
      #pragma unroll
      for (int fj = 0; fj < 2; fj++){
        acc[fi][fj] = __builtin_amdgcn_mfma_f32_16x16x32_bf16(fah[fi], fbh[fj], acc[fi][fj], 0,0,0);
        acc[fi][fj] = __builtin_amdgcn_mfma_f32_16x16x32_bf16(fah[fi], fbl[fj], acc[fi][fj], 0,0,0);
        acc[fi][fj] = __builtin_amdgcn_mfma_f32_16x16x32_bf16(fal[fi], fbh[fj], acc[fi][fj], 0,0,0);
      }
    __syncthreads();
  }
  float* dst = Vp + (size_t)blockIdx.z*NDIM*NDIM;
  #pragma unroll
  for (int fi = 0; fi < 2; fi++)
    #pragma unroll
    for (int fj = 0; fj < 2; fj++)
      #pragma unroll
      for (int e = 0; e < 4; e++){
        int gi = i0 + wr*32 + fi*16 + (lane>>4)*4 + e;
        int gj = j0 + wc*32 + fj*16 + lrow;
        dst[(size_t)gi*NDIM + gj] = acc[fi][fj][e];
      }
}

// ------- reduce partials: V = sum_z Vp[z] / 4095 -------
__global__ void k_Vred(const float* __restrict__ Vp, float* __restrict__ V){
  int idx = (blockIdx.x*256 + threadIdx.x)*4;
  const size_t S = (size_t)NDIM*NDIM;
  float4 a = *(const float4*)(Vp+idx);
  float4 b = *(const float4*)(Vp+S+idx);
  float4 c = *(const float4*)(Vp+2*S+idx);
  float4 d = *(const float4*)(Vp+3*S+idx);
  const float s = 1.0f/4095.0f;
  float4 o;
  o.x = (a.x+b.x+c.x+d.x)*s; o.y = (a.y+b.y+c.y+d.y)*s;
  o.z = (a.z+b.z+c.z+d.z)*s; o.w = (a.w+b.w+c.w+d.w)*s;
  *(float4*)(V+idx) = o;
}

// ------- ||V||_1 pieces -------
__global__ void k_norm1_rows(const float* __restrict__ V, float* __restrict__ rowsum){
  int rr = blockIdx.x; int lane = threadIdx.x; // 64 threads
  const float4* row = (const float4*)(V + (size_t)rr*NDIM);
  float s = 0.f;
  for (int c = lane; c < NDIM/4; c += 64){
    float4 v = row[c];
    s += fabsf(v.x)+fabsf(v.y)+fabsf(v.z)+fabsf(v.w);
  }
  #pragma unroll
  for (int off = 32; off > 0; off >>= 1) s += __shfl_down(s, off, 64);
  if (lane == 0) rowsum[rr] = s;
}
__global__ void k_rinv(const float* __restrict__ rowsum, float* __restrict__ rinv){
  __shared__ float red[512];
  int t = threadIdx.x;
  red[t] = rowsum[t]; __syncthreads();
  for (int off = 256; off > 0; off >>= 1){
    if (t < off) red[t] = fmaxf(red[t], red[t+off]);
    __syncthreads();
  }
  if (t == 0) rinv[0] = 1.0f / red[0];
}
__global__ void k_nsinit(const float* __restrict__ rinv, float* __restrict__ Y){
  int r = blockIdx.x;
  float c = rinv[0];
  for (int j = threadIdx.x; j < NDIM; j += 256)
    Y[(size_t)r*NDIM + j] = (j == r) ? c : 0.f;
}

// ------- 512^3 MFMA GEMM on f32 operands (in-register bf16 split; B transpose-staged) -------
// MODE 0: C = A*B (plain)   MODE 1: C = 2A - A*B (plain)
// MODE 2: C = I - A*B (hi/lo precise)   MODE 3: C = A + A*B (plain)
template<int MODE>
__global__ __launch_bounds__(256) void k_g512(const float* __restrict__ A,
     const float* __restrict__ B, float* __restrict__ C){
  const bool PREC = (MODE == 2);
  __shared__ __align__(16) unsigned short Ah[64*40], Al[64*40];
  __shared__ __align__(16) unsigned short Bh[64*40], Bl[64*40];
  int i0 = blockIdx.x*64, j0 = blockIdx.y*64;
  int t = threadIdx.x, lane = t&63, wave = t>>6;
  int wr = wave>>1, wc = wave&1;
  int lrow = lane & 15, kc = (lane>>4)*8;
  f32x4 acc[2][2];
  #pragma unroll
  for (int a = 0; a < 2; a++)
    #pragma unroll
    for (int b = 0; b < 2; b++) acc[a][b] = (f32x4){0.f,0.f,0.f,0.f};
  int r = t>>2, c8 = (t&3)*8;          // A mapping: row i0+r, k cols c8..c8+7
  int kB = t>>3, c8b = (t&7)*8;        // B mapping: k row kB, cols j0+c8b..+7
  const float* pA = A + (size_t)(i0+r)*NDIM + c8;
  const float* pB = B + (size_t)kB*NDIM + j0 + c8b;
  float4 a0_ = *(const float4*)pA, a1_ = *(const float4*)(pA+4);
  float4 b0_ = *(const float4*)pB, b1_ = *(const float4*)(pB+4);
  for (int kt = 0; kt < 16; kt++){
    float av[8] = {a0_.x,a0_.y,a0_.z,a0_.w,a1_.x,a1_.y,a1_.z,a1_.w};
    float bv[8] = {b0_.x,b0_.y,b0_.z,b0_.w,b1_.x,b1_.y,b1_.z,b1_.w};
    unsigned short h8[8] __attribute__((aligned(16)));
    unsigned short l8[8] __attribute__((aligned(16)));
    #pragma unroll
    for (int e = 0; e < 8; e++){
      h8[e] = f2bf(av[e]);
      if (PREC) l8[e] = f2bf(av[e] - bf2f(h8[e]));
    }
    *(uint4*)&Ah[r*40 + c8] = *(uint4*)h8;
    if (PREC) *(uint4*)&Al[r*40 + c8] = *(uint4*)l8;
    #pragma unroll
    for (int e = 0; e < 8; e++){
      unsigned short hh = f2bf(bv[e]);
      Bh[(c8b+e)*40 + kB] = hh;
      if (PREC) Bl[(c8b+e)*40 + kB] = f2bf(bv[e] - bf2f(hh));
    }
    __syncthreads();
    if (kt < 15){
      pA += 32; pB += 32*NDIM;
      a0_ = *(const float4*)pA; a1_ = *(const float4*)(pA+4);
      b0_ = *(const float4*)pB; b1_ = *(const float4*)(pB+4);
    }
    short8 fah[2], fbh[2], fal[2], fbl[2];
    #pragma unroll
    for (int f = 0; f < 2; f++){
      fah[f] = *(const short8*)&Ah[(wr*32 + f*16 + lrow)*40 + kc];
      fbh[f] = *(const short8*)&Bh[(wc*32 + f*16 + lrow)*40 + kc];
      if (PREC){
        fal[f] = *(const short8*)&Al[(wr*32 + f*16 + lrow)*40 + kc];
        fbl[f] = *(const short8*)&Bl[(wc*32 + f*16 + lrow)*40 + kc];
      }
    }
    #pragma unroll
    for (int fi = 0; fi < 2; fi++)
      #pragma unroll
      for (int fj = 0; fj < 2; fj++){
        acc[fi][fj] = __builtin_amdgcn_mfma_f32_16x16x32_bf16(fah[fi], fbh[fj], acc[fi][fj], 0,0,0);
        if (PREC){
          acc[fi][fj] = __builtin_amdgcn_mfma_f32_16x16x32_bf16(fah[fi], fbl[fj], acc[fi][fj], 0,0,0);
          acc[fi][fj] = __builtin_amdgcn_mfma_f32_16x16x32_bf16(fal[fi], fbh[fj], acc[fi][fj], 0,0,0);
        }
      }
    __syncthreads();
  }
  #pragma unroll
  for (int fi = 0; fi < 2; fi++)
    #pragma unroll
    for (int fj = 0; fj < 2; fj++)
      #pragma unroll
      for (int e = 0; e < 4; e++){
        int gi = i0 + wr*32 + fi*16 + (lane>>4)*4 + e;
        int gj = j0 + wc*32 + fj*16 + lrow;
        float v = acc[fi][fj][e];
        size_t o = (size_t)gi*NDIM + gj;
        if (MODE == 0) C[o] = v;
        else if (MODE == 1) C[o] = 2.f*A[o] - v;
        else if (MODE == 2) C[o] = ((gi==gj)?1.f:0.f) - v;
        else C[o] = A[o] + v;
      }
}

// ------- split VI (f32) into bf16 hi/lo -------
__global__ void k_splitVI(const float* __restrict__ Y, unsigned short* __restrict__ Vh,
                          unsigned short* __restrict__ Vl){
  int idx = (blockIdx.x*256 + threadIdx.x)*4;
  float4 v = *(const float4*)(Y+idx);
  unsigned short h4[4] __attribute__((aligned(8)));
  unsigned short l4[4] __attribute__((aligned(8)));
  float vv[4] = {v.x, v.y, v.z, v.w};
  #pragma unroll
  for (int e = 0; e < 4; e++){
    h4[e] = f2bf(vv[e]); l4[e] = f2bf(vv[e] - bf2f(h4[e]));
  }
  *(uint2*)&Vh[idx] = *(uint2*)h4;
  *(uint2*)&Vl[idx] = *(uint2*)l4;
}

// ------- Zt[i][a] = bf16( (Xt VI^T)[i][a] )  hi/lo on both sides -------
__global__ __launch_bounds__(256) void k_gemmZ(const unsigned short* __restrict__ Xth,
    const unsigned short* __restrict__ Xtl, const unsigned short* __restrict__ VIh,
    const unsigned short* __restrict__ VIl, unsigned short* __restrict__ Zt){
  __shared__ __align__(16) unsigned short Ah[64*40], Al[64*40], Bh[64*40], Bl[64*40];
  int i0 = blockIdx.x*64, j0 = blockIdx.y*64;
  int t = threadIdx.x, lane = t&63, wave = t>>6;
  int wr = wave>>1, wc = wave&1;
  int lrow = lane & 15, kc = (lane>>4)*8;
  f32x4 acc[2][2];
  #pragma unroll
  for (int a = 0; a < 2; a++)
    #pragma unroll
    for (int b = 0; b < 2; b++) acc[a][b] = (f32x4){0.f,0.f,0.f,0.f};
  int r = t>>2, c8 = (t&3)*8;
  const unsigned short* pAh = Xth + (size_t)(i0+r)*NDIM + c8;
  const unsigned short* pAl = Xtl + (size_t)(i0+r)*NDIM + c8;
  const unsigned short* pBh = VIh + (size_t)(j0+r)*NDIM + c8;
  const unsigned short* pBl = VIl + (size_t)(j0+r)*NDIM + c8;
  uint4 ra_h = *(const uint4*)pAh, ra_l = *(const uint4*)pAl;
  uint4 rb_h = *(const uint4*)pBh, rb_l = *(const uint4*)pBl;
  for (int kt = 0; kt < 16; kt++){
    *(uint4*)&Ah[r*40 + c8] = ra_h;
    *(uint4*)&Al[r*40 + c8] = ra_l;
    *(uint4*)&Bh[r*40 + c8] = rb_h;
    *(uint4*)&Bl[r*40 + c8] = rb_l;
    __syncthreads();
    if (kt < 15){
      pAh += 32; pAl += 32; pBh += 32; pBl += 32;
      ra_h = *(const uint4*)pAh; ra_l = *(const uint4*)pAl;
      rb_h = *(const uint4*)pBh; rb_l = *(const uint4*)pBl;
    }
    short8 fah[2], fal[2], fbh[2], fbl[2];
    #pragma unroll
    for (int f = 0; f < 2; f++){
      fah[f] = *(const short8*)&Ah[(wr*32 + f*16 + lrow)*40 + kc];
      fal[f] = *(const short8*)&Al[(wr*32 + f*16 + lrow)*40 + kc];
      fbh[f] = *(const short8*)&Bh[(wc*32 + f*16 + lrow)*40 + kc];
      fbl[f] = *(const short8*)&Bl[(wc*32 + f*16 + lrow)*40 + kc];
    }
    #pragma unroll
    for (int fi = 0; fi < 2; fi++)
      #pragma unroll
      for (int fj = 0; fj < 2; fj++){
        acc[fi][fj] = __builtin_amdgcn_mfma_f32_16x16x32_bf16(fah[fi], fbh[fj], acc[fi][fj], 0,0,0);
        acc[fi][fj] = __builtin_amdgcn_mfma_f32_16x16x32_bf16(fah[fi], fbl[fj], acc[fi][fj], 0,0,0);
        acc[fi][fj] = __builtin_amdgcn_mfma_f32_16x16x32_bf16(fal[fi], fbh[fj], acc[fi][fj], 0,0,0);
      }
    __syncthreads();
  }
  #pragma unroll
  for (int fi = 0; fi < 2; fi++)
    #pragma unroll
    for (int fj = 0; fj < 2; fj++)
      #pragma unroll
      for (int e = 0; e < 4; e++){
        int gi = i0 + wr*32 + fi*16 + (lane>>4)*4 + e;
        int gj = j0 + wc*32 + fj*16 + lrow;
        Zt[(size_t)gi*NDIM + gj] = f2bf(acc[fi][fj][e]);
      }
}

// ---------------- q[i] = dot(Xth[i,:], Zt[i,:]) ----------------
__global__ void k_q(const unsigned short* __restrict__ Xt, const unsigned short* __restrict__ Zt,
                    float* __restrict__ q){
  int wave = threadIdx.x >> 6, lane = threadIdx.x & 63;
  int i = blockIdx.x * 4 + wave;
  uint4 xv = *(const uint4*)(Xt + (size_t)i*NDIM + lane*8);
  uint4 zv = *(const uint4*)(Zt + (size_t)i*NDIM + lane*8);
  const unsigned short* xs = (const unsigned short*)&xv;
  const unsigned short* zs = (const unsigned short*)&zv;
  float s = 0.f;
  #pragma unroll
  for (int e = 0; e < 8; e++) s += bf2f(xs[e]) * bf2f(zs[e]);
  #pragma unroll
  for (int off = 32; off > 0; off >>= 1) s += __shfl_down(s, off, 64);
  if (lane == 0) q[i] = s;
}

// ---------------- G tiles (bf16 MFMA) + distance epilogue ----------------
__global__ __launch_bounds__(256) void k_G(const unsigned short* __restrict__ Xt,
        const unsigned short* __restrict__ Zt, const float* __restrict__ q,
        float* __restrict__ out){
  int ti = blockIdx.x, tj = blockIdx.y;
  if (tj < ti) return;
  __shared__ __align__(16) unsigned short At[128*40];
  __shared__ __align__(16) unsigned short Bt[128*40];
  int t = threadIdx.x;
  int lane = t & 63, wave = t >> 6;
  int wr = wave >> 1, wc = wave & 1;
  f32x4 acc[4][4];
  #pragma unroll
  for (int a = 0; a < 4; a++)
    #pragma unroll
    for (int b = 0; b < 4; b++)
      acc[a][b] = (f32x4){0.f,0.f,0.f,0.f};
  int i0 = ti * 128, j0 = tj * 128;
  for (int kb = 0; kb < NDIM; kb += 32){
    __syncthreads();
    #pragma unroll
    for (int s = 0; s < 2; s++){
      int id = t + s*256;
      int r = id >> 2, c8 = (id & 3) * 8;
      *(uint4*)&At[r*40 + c8] = *(const uint4*)(Xt + (size_t)(i0+r)*NDIM + kb + c8);
      *(uint4*)&Bt[r*40 + c8] = *(const uint4*)(Zt + (size_t)(j0+r)*NDIM + kb + c8);
    }
    __syncthreads();
    short8 af[4], bfr[4];
    #pragma unroll
    for (int f = 0; f < 4; f++){
      af[f]  = *(const short8*)&At[(wr*64 + f*16 + (lane & 15))*40 + (lane >> 4)*8];
      bfr[f] = *(const short8*)&Bt[(wc*64 + f*16 + (lane & 15))*40 + (lane >> 4)*8];
    }
    #pragma unroll
    for (int fi = 0; fi < 4; fi++)
      #pragma unroll
      for (int fj = 0; fj < 4; fj++)
        acc[fi][fj] = __builtin_amdgcn_mfma_f32_16x16x32_bf16(af[fi], bfr[fj], acc[fi][fj], 0, 0, 0);
  }
  #pragma unroll
  for (int fi = 0; fi < 4; fi++){
    #pragma unroll
    for (int fj = 0; fj < 4; fj++){
      #pragma unroll
      for (int e = 0; e < 4; e++){
        int gi = i0 + wr*64 + fi*16 + (lane >> 4)*4 + e;
        int gj = j0 + wc*64 + fj*16 + (lane & 15);
        if (gi < gj){
          float d2 = q[gi] + q[gj] - 2.0f * acc[fi][fj][e];
          size_t idx = (size_t)gi * NPTS - ((size_t)gi*(gi+1))/2 + (size_t)(gj - gi - 1);
          out[idx] = sqrtf(fmaxf(d2, 1e-12f));
        }
      }
    }
  }
}

extern "C" void kernel_launch(void* const* d_in, const int* in_sizes, int n_in,
                              void* d_out, int out_size, void* d_ws, size_t ws_size,
                              hipStream_t stream) {
  (void)in_sizes; (void)n_in; (void)out_size; (void)ws_size;
  const float* x0 = (const float*)d_in[0];
  const float* x1 = (const float*)d_in[1];
  float* out = (float*)d_out;

  char* w = (char*)d_ws;
  float* mu     = (float*)w; w += 4096;
  float* rinv   = (float*)w; w += 4096;
  float* rowsum = (float*)w; w += 4096;
  float* V  = (float*)w; w += (size_t)NDIM*NDIM*4;
  float* Y0 = (float*)w; w += (size_t)NDIM*NDIM*4;
  float* Y1 = (float*)w; w += (size_t)NDIM*NDIM*4;
  float* T  = (float*)w; w += (size_t)NDIM*NDIM*4;
  float* q  = (float*)w; w += NPTS*4;
  unsigned short* VIh = (unsigned short*)w; w += (size_t)NDIM*NDIM*2;
  unsigned short* VIl = (unsigned short*)w; w += (size_t)NDIM*NDIM*2;
  unsigned short* Xch = (unsigned short*)w; w += (size_t)NDIM*NPTS*2;
  unsigned short* Xcl = (unsigned short*)w; w += (size_t)NDIM*NPTS*2;
  unsigned short* Xth = (unsigned short*)w; w += (size_t)NDIM*NPTS*2;
  unsigned short* Xtl = (unsigned short*)w; w += (size_t)NDIM*NPTS*2;
  unsigned short* Zt  = (unsigned short*)w; w += (size_t)NDIM*NPTS*2;
  float* Vp = (float*)Zt;  // alias: 4 x 1MB partials = 4MB, dead before Zt is written

  k_rowmean<<<dim3(512), dim3(256), 0, stream>>>(x0, x1, mu);
  k_prep<<<dim3(64,8), dim3(256), 0, stream>>>(x0, x1, mu, Xch, Xcl, Xth, Xtl);
  k_V_mfma<<<dim3(8,8,KSPLIT), dim3(256), 0, stream>>>(Xch, Xcl, Vp);
  k_Vred<<<dim3(256), dim3(256), 0, stream>>>(Vp, V);
  k_norm1_rows<<<dim3(512), dim3(64), 0, stream>>>(V, rowsum);
  k_rinv<<<dim3(1), dim3(512), 0, stream>>>(rowsum, rinv);
  k_nsinit<<<dim3(512), dim3(256), 0, stream>>>(rinv, Y0);

  float* cur = Y0; float* nxt = Y1;
  for (int it = 0; it < 7; ++it){
    k_g512<0><<<dim3(8,8), dim3(256), 0, stream>>>(V, cur, T);
    k_g512<1><<<dim3(8,8), dim3(256), 0, stream>>>(cur, T, nxt);
    float* tmp = cur; cur = nxt; nxt = tmp;
  }
  for (int it = 0; it < 2; ++it){
    k_g512<2><<<dim3(8,8), dim3(256), 0, stream>>>(V, cur, T);
    k_g512<3><<<dim3(8,8), dim3(256), 0, stream>>>(cur, T, nxt);
    float* tmp = cur; cur = nxt; nxt = tmp;
  }
  k_splitVI<<<dim3(256), dim3(256), 0, stream>>>(cur, VIh, VIl);
  k_gemmZ<<<dim3(64,8), dim3(256), 0, stream>>>(Xth, Xtl, VIh, VIl, Zt);
  k_q<<<dim3(1024), dim3(256), 0, stream>>>(Xth, Zt, q);
  k_G<<<dim3(32,32), dim3(256), 0, stream>>>(Xth, Zt, q, out);
}

// Round 3
// 193.347 us; speedup vs baseline: 3.6376x; 1.8112x over previous
//
#include <hip/hip_runtime.h>
#include <hip/hip_bf16.h>
#include <math.h>

#define NDIM 512
#define NPTS 4096
#define KSPLIT 8

typedef __attribute__((ext_vector_type(4))) float f32x4;
typedef __attribute__((ext_vector_type(8))) short short8;

__device__ __forceinline__ const float* xrow(const float* x0, const float* x1, int r){
  return (r < 256) ? (x0 + (size_t)r * NPTS) : (x1 + (size_t)(r - 256) * NPTS);
}
__device__ __forceinline__ unsigned short f2bf(float f){
  __hip_bfloat16 h = __float2bfloat16(f);
  return *reinterpret_cast<unsigned short*>(&h);
}
__device__ __forceinline__ float bf2f(unsigned short u){
  return __uint_as_float(((unsigned int)u) << 16);
}
__device__ __forceinline__ void gload16(const void* g, void* l){
  __builtin_amdgcn_global_load_lds((const __attribute__((address_space(1))) void*)g,
                                   (__attribute__((address_space(3))) void*)l, 16, 0, 0);
}

// ---------------- row means of X (512 rows x 4096) ----------------
__global__ void k_rowmean(const float* __restrict__ x0, const float* __restrict__ x1,
                          float* __restrict__ mu){
  int r = blockIdx.x;
  const float4* row4 = (const float4*)xrow(x0, x1, r);
  float s = 0.f;
  for (int c = threadIdx.x; c < NPTS/4; c += 256){
    float4 v = row4[c];
    s += v.x + v.y + v.z + v.w;
  }
  __shared__ float red[256];
  red[threadIdx.x] = s; __syncthreads();
  for (int off = 128; off > 0; off >>= 1){
    if (threadIdx.x < off) red[threadIdx.x] += red[threadIdx.x + off];
    __syncthreads();
  }
  if (threadIdx.x == 0) mu[r] = red[0] * (1.0f / NPTS);
}

// ------- prep: centered X in bf16 hi/lo, both layouts -------
__global__ __launch_bounds__(256) void k_prep(const float* __restrict__ x0, const float* __restrict__ x1,
      const float* __restrict__ mu,
      unsigned short* __restrict__ Xch, unsigned short* __restrict__ Xcl,
      unsigned short* __restrict__ Xth, unsigned short* __restrict__ Xtl){
  __shared__ float tile[64][65];
  int i0 = blockIdx.x * 64, a0 = blockIdx.y * 64;
  int t = threadIdx.x;
  int r = t >> 2, cg = (t & 3) * 16;
  const float* row = xrow(x0, x1, a0 + r);
  float m = mu[a0 + r];
  unsigned short h16[16] __attribute__((aligned(16)));
  unsigned short l16[16] __attribute__((aligned(16)));
  #pragma unroll
  for (int e = 0; e < 16; e += 4){
    float4 v = *(const float4*)(row + i0 + cg + e);
    v.x -= m; v.y -= m; v.z -= m; v.w -= m;
    tile[r][cg+e] = v.x; tile[r][cg+e+1] = v.y; tile[r][cg+e+2] = v.z; tile[r][cg+e+3] = v.w;
    h16[e]   = f2bf(v.x); l16[e]   = f2bf(v.x - bf2f(h16[e]));
    h16[e+1] = f2bf(v.y); l16[e+1] = f2bf(v.y - bf2f(h16[e+1]));
    h16[e+2] = f2bf(v.z); l16[e+2] = f2bf(v.z - bf2f(h16[e+2]));
    h16[e+3] = f2bf(v.w); l16[e+3] = f2bf(v.w - bf2f(h16[e+3]));
  }
  unsigned short* dst = Xch + (size_t)(a0+r)*NPTS + i0 + cg;
  *(uint4*)dst = *(uint4*)&h16[0]; *(uint4*)(dst+8) = *(uint4*)&h16[8];
  dst = Xcl + (size_t)(a0+r)*NPTS + i0 + cg;
  *(uint4*)dst = *(uint4*)&l16[0]; *(uint4*)(dst+8) = *(uint4*)&l16[8];
  __syncthreads();
  unsigned short th[16] __attribute__((aligned(16)));
  unsigned short tl[16] __attribute__((aligned(16)));
  #pragma unroll
  for (int e = 0; e < 16; e++){
    float v = tile[cg+e][r];
    th[e] = f2bf(v); tl[e] = f2bf(v - bf2f(th[e]));
  }
  unsigned short* d2 = Xth + (size_t)(i0 + r)*NDIM + a0 + cg;
  *(uint4*)d2 = *(uint4*)&th[0]; *(uint4*)(d2+8) = *(uint4*)&th[8];
  d2 = Xtl + (size_t)(i0 + r)*NDIM + a0 + cg;
  *(uint4*)d2 = *(uint4*)&tl[0]; *(uint4*)(d2+8) = *(uint4*)&tl[8];
}

// ------- V partials, upper-triangle tiles only, mirror-written -------
__global__ __launch_bounds__(256) void k_V_mfma(const unsigned short* __restrict__ Xch,
        const unsigned short* __restrict__ Xcl, float* __restrict__ Vp){
  int b = blockIdx.x;
  int ti = 0, rem = b;
  while (rem >= 8 - ti){ rem -= 8 - ti; ti++; }
  int tj = ti + rem;
  int i0 = ti*64, j0 = tj*64;
  int z = blockIdx.y;
  __shared__ __align__(16) unsigned short Ah[64*40], Al[64*40], Bh[64*40], Bl[64*40];
  int t = threadIdx.x, lane = t&63, wave = t>>6;
  int wr = wave>>1, wc = wave&1;
  int lrow = lane & 15, kc = (lane>>4)*8;
  f32x4 acc[2][2];
  #pragma unroll
  for (int a = 0; a < 2; a++)
    #pragma unroll
    for (int c = 0; c < 2; c++) acc[a][c] = (f32x4){0.f,0.f,0.f,0.f};
  int r = t>>2, c8 = (t&3)*8;
  size_t kbase = (size_t)z * (NPTS/KSPLIT);
  const unsigned short* pAh = Xch + (size_t)(i0+r)*NPTS + kbase + c8;
  const unsigned short* pAl = Xcl + (size_t)(i0+r)*NPTS + kbase + c8;
  const unsigned short* pBh = Xch + (size_t)(j0+r)*NPTS + kbase + c8;
  const unsigned short* pBl = Xcl + (size_t)(j0+r)*NPTS + kbase + c8;
  uint4 ra_h = *(const uint4*)pAh, ra_l = *(const uint4*)pAl;
  uint4 rb_h = *(const uint4*)pBh, rb_l = *(const uint4*)pBl;
  const int NK = (NPTS/KSPLIT)/32;
  for (int kt = 0; kt < NK; kt++){
    *(uint4*)&Ah[r*40 + c8] = ra_h;
    *(uint4*)&Al[r*40 + c8] = ra_l;
    *(uint4*)&Bh[r*40 + c8] = rb_h;
    *(uint4*)&Bl[r*40 + c8] = rb_l;
    __syncthreads();
    if (kt+1 < NK){
      pAh += 32; pAl += 32; pBh += 32; pBl += 32;
      ra_h = *(const uint4*)pAh; ra_l = *(const uint4*)pAl;
      rb_h = *(const uint4*)pBh; rb_l = *(const uint4*)pBl;
    }
    short8 fah[2], fal[2], fbh[2], fbl[2];
    #pragma unroll
    for (int f = 0; f < 2; f++){
      fah[f] = *(const short8*)&Ah[(wr*32 + f*16 + lrow)*40 + kc];
      fal[f] = *(const short8*)&Al[(wr*32 + f*16 + lrow)*40 + kc];
      fbh[f] = *(const short8*)&Bh[(wc*32 + f*16 + lrow)*40 + kc];
      fbl[f] = *(const short8*)&Bl[(wc*32 + f*16 + lrow)*40 + kc];
    }
    #pragma unroll
    for (int fi = 0; fi < 2; fi++)
      #pragma unroll
      for (int fj = 0; fj < 2; fj++){
        acc[fi][fj] = __builtin_amdgcn_mfma_f32_16x16x32_bf16(fah[fi], fbh[fj], acc[fi][fj], 0,0,0);
        acc[fi][fj] = __builtin_amdgcn_mfma_f32_16x16x32_bf16(fah[fi], fbl[fj], acc[fi][fj], 0,0,0);
        acc[fi][fj] = __builtin_amdgcn_mfma_f32_16x16x32_bf16(fal[fi], fbh[fj], acc[fi][fj], 0,0,0);
      }
    __syncthreads();
  }
  float* dst = Vp + (size_t)z*NDIM*NDIM;
  #pragma unroll
  for (int fi = 0; fi < 2; fi++)
    #pragma unroll
    for (int fj = 0; fj < 2; fj++)
      #pragma unroll
      for (int e = 0; e < 4; e++){
        int gi = i0 + wr*32 + fi*16 + (lane>>4)*4 + e;
        int gj = j0 + wc*32 + fj*16 + lrow;
        dst[(size_t)gi*NDIM + gj] = acc[fi][fj][e];
        if (ti != tj) dst[(size_t)gj*NDIM + gi] = acc[fi][fj][e];
      }
}

// ------- finV: V = sum_z Vp[z]/4095 ; rowsum = sum_j |V[r][j]| -------
__global__ void k_finV(const float* __restrict__ Vp, float* __restrict__ V,
                       float* __restrict__ rowsum){
  int r = blockIdx.x, lane = threadIdx.x; // 64 threads
  const size_t S = (size_t)NDIM*NDIM;
  float a[8] = {0,0,0,0,0,0,0,0};
  #pragma unroll
  for (int z = 0; z < KSPLIT; z++){
    const float* p = Vp + z*S + (size_t)r*NDIM + lane*8;
    float4 u = *(const float4*)p;
    float4 v = *(const float4*)(p+4);
    a[0]+=u.x; a[1]+=u.y; a[2]+=u.z; a[3]+=u.w;
    a[4]+=v.x; a[5]+=v.y; a[6]+=v.z; a[7]+=v.w;
  }
  const float s = 1.0f/4095.0f;
  float asum = 0.f;
  #pragma unroll
  for (int e = 0; e < 8; e++){ a[e] *= s; asum += fabsf(a[e]); }
  float* dst = V + (size_t)r*NDIM + lane*8;
  *(float4*)dst = (float4){a[0],a[1],a[2],a[3]};
  *(float4*)(dst+4) = (float4){a[4],a[5],a[6],a[7]};
  #pragma unroll
  for (int off = 32; off > 0; off >>= 1) asum += __shfl_down(asum, off, 64);
  if (lane == 0) rowsum[r] = asum;
}

__global__ void k_rinv(const float* __restrict__ rowsum, float* __restrict__ rinv){
  __shared__ float red[512];
  int t = threadIdx.x;
  red[t] = rowsum[t]; __syncthreads();
  for (int off = 256; off > 0; off >>= 1){
    if (t < off) red[t] = fmaxf(red[t], red[t+off]);
    __syncthreads();
  }
  if (t == 0) rinv[0] = 1.0f / red[0];
}

// ------- init: E0 = I - cV, P0 = cI (bf16); Vh/Vl hi-lo split of V -------
__global__ void k_initEP(const float* __restrict__ V, const float* __restrict__ rinv,
      unsigned short* __restrict__ E0, unsigned short* __restrict__ P0,
      unsigned short* __restrict__ Vh, unsigned short* __restrict__ Vl){
  int r = blockIdx.x, lane = threadIdx.x; // 64 threads
  float c = rinv[0];
  const float* src = V + (size_t)r*NDIM + lane*8;
  unsigned short vh[8] __attribute__((aligned(16))), vl[8] __attribute__((aligned(16)));
  unsigned short e8[8] __attribute__((aligned(16))), p8[8] __attribute__((aligned(16)));
  #pragma unroll
  for (int e = 0; e < 8; e++){
    float v = src[e];
    vh[e] = f2bf(v); vl[e] = f2bf(v - bf2f(vh[e]));
    int col = lane*8 + e;
    float ev = ((col==r)?1.f:0.f) - c*v;
    e8[e] = f2bf(ev);
    p8[e] = f2bf((col==r)?c:0.f);
  }
  size_t o = (size_t)r*NDIM + lane*8;
  *(uint4*)&Vh[o] = *(uint4*)vh; *(uint4*)&Vl[o] = *(uint4*)vl;
  *(uint4*)&E0[o] = *(uint4*)e8; *(uint4*)&P0[o] = *(uint4*)p8;
}

// ------- fused NS iteration: blocks 0-63: En = E*E ; 64-127: Pn = P + P*E -------
__global__ __launch_bounds__(256) void k_ns(const unsigned short* __restrict__ E,
      const unsigned short* __restrict__ P,
      unsigned short* __restrict__ En, unsigned short* __restrict__ Pn){
  int b = blockIdx.x;
  int half = b >> 6, tile = b & 63;
  int i0 = (tile>>3)*64, j0 = (tile&7)*64;
  const unsigned short* Asrc = half ? P : E;
  __shared__ __align__(16) unsigned short Ah[64*40], Bh[64*40];
  int t = threadIdx.x, lane = t&63, wave = t>>6;
  int wr = wave>>1, wc = wave&1;
  int lrow = lane & 15, kc = (lane>>4)*8;
  f32x4 acc[2][2];
  #pragma unroll
  for (int a = 0; a < 2; a++)
    #pragma unroll
    for (int c = 0; c < 2; c++) acc[a][c] = (f32x4){0.f,0.f,0.f,0.f};
  int r = t>>2, c8 = (t&3)*8;
  const unsigned short* pA = Asrc + (size_t)(i0+r)*NDIM + c8;
  const unsigned short* pB = E + (size_t)(j0+r)*NDIM + c8;
  uint4 ra = *(const uint4*)pA, rb = *(const uint4*)pB;
  for (int kt = 0; kt < 16; kt++){
    *(uint4*)&Ah[r*40 + c8] = ra;
    *(uint4*)&Bh[r*40 + c8] = rb;
    __syncthreads();
    if (kt < 15){
      pA += 32; pB += 32;
      ra = *(const uint4*)pA; rb = *(const uint4*)pB;
    }
    short8 fa[2], fb[2];
    #pragma unroll
    for (int f = 0; f < 2; f++){
      fa[f] = *(const short8*)&Ah[(wr*32 + f*16 + lrow)*40 + kc];
      fb[f] = *(const short8*)&Bh[(wc*32 + f*16 + lrow)*40 + kc];
    }
    #pragma unroll
    for (int fi = 0; fi < 2; fi++)
      #pragma unroll
      for (int fj = 0; fj < 2; fj++)
        acc[fi][fj] = __builtin_amdgcn_mfma_f32_16x16x32_bf16(fa[fi], fb[fj], acc[fi][fj], 0,0,0);
    __syncthreads();
  }
  #pragma unroll
  for (int fi = 0; fi < 2; fi++)
    #pragma unroll
    for (int fj = 0; fj < 2; fj++)
      #pragma unroll
      for (int e = 0; e < 4; e++){
        int gi = i0 + wr*32 + fi*16 + (lane>>4)*4 + e;
        int gj = j0 + wc*32 + fj*16 + lrow;
        size_t o = (size_t)gi*NDIM + gj;
        if (half) Pn[o] = f2bf(bf2f(P[o]) + acc[fi][fj][e]);
        else      En[o] = f2bf(acc[fi][fj][e]);
      }
}

// ------- resid: R = I - (Vh+Vl)*P, stored TRANSPOSED as hi/lo bf16 -------
__global__ __launch_bounds__(256) void k_resid(const unsigned short* __restrict__ Vh,
      const unsigned short* __restrict__ Vl, const unsigned short* __restrict__ P,
      unsigned short* __restrict__ Rh, unsigned short* __restrict__ Rl){
  int b = blockIdx.x;
  int i0 = (b>>3)*64, j0 = (b&7)*64;
  __shared__ __align__(16) unsigned short Ah[64*40], Al[64*40], Bh[64*40];
  int t = threadIdx.x, lane = t&63, wave = t>>6;
  int wr = wave>>1, wc = wave&1;
  int lrow = lane & 15, kc = (lane>>4)*8;
  f32x4 acc[2][2];
  #pragma unroll
  for (int a = 0; a < 2; a++)
    #pragma unroll
    for (int c = 0; c < 2; c++) acc[a][c] = (f32x4){0.f,0.f,0.f,0.f};
  int r = t>>2, c8 = (t&3)*8;
  const unsigned short* pAh = Vh + (size_t)(i0+r)*NDIM + c8;
  const unsigned short* pAl = Vl + (size_t)(i0+r)*NDIM + c8;
  const unsigned short* pB  = P  + (size_t)(j0+r)*NDIM + c8;
  uint4 rah = *(const uint4*)pAh, ral = *(const uint4*)pAl, rb = *(const uint4*)pB;
  for (int kt = 0; kt < 16; kt++){
    *(uint4*)&Ah[r*40 + c8] = rah;
    *(uint4*)&Al[r*40 + c8] = ral;
    *(uint4*)&Bh[r*40 + c8] = rb;
    __syncthreads();
    if (kt < 15){
      pAh += 32; pAl += 32; pB += 32;
      rah = *(const uint4*)pAh; ral = *(const uint4*)pAl; rb = *(const uint4*)pB;
    }
    short8 fah[2], fal[2], fb[2];
    #pragma unroll
    for (int f = 0; f < 2; f++){
      fah[f] = *(const short8*)&Ah[(wr*32 + f*16 + lrow)*40 + kc];
      fal[f] = *(const short8*)&Al[(wr*32 + f*16 + lrow)*40 + kc];
      fb[f]  = *(const short8*)&Bh[(wc*32 + f*16 + lrow)*40 + kc];
    }
    #pragma unroll
    for (int fi = 0; fi < 2; fi++)
      #pragma unroll
      for (int fj = 0; fj < 2; fj++){
        acc[fi][fj] = __builtin_amdgcn_mfma_f32_16x16x32_bf16(fah[fi], fb[fj], acc[fi][fj], 0,0,0);
        acc[fi][fj] = __builtin_amdgcn_mfma_f32_16x16x32_bf16(fal[fi], fb[fj], acc[fi][fj], 0,0,0);
      }
    __syncthreads();
  }
  #pragma unroll
  for (int fi = 0; fi < 2; fi++)
    #pragma unroll
    for (int fj = 0; fj < 2; fj++)
      #pragma unroll
      for (int e = 0; e < 4; e++){
        int gi = i0 + wr*32 + fi*16 + (lane>>4)*4 + e;
        int gj = j0 + wc*32 + fj*16 + lrow;
        float rv = ((gi==gj)?1.f:0.f) - acc[fi][fj][e];
        unsigned short hi = f2bf(rv);
        size_t o = (size_t)gj*NDIM + gi;   // transposed store
        Rh[o] = hi; Rl[o] = f2bf(rv - bf2f(hi));
      }
}

// ------- final: VI = P + P*R (R rows = R columns, stored transposed) -> VIh/VIl -------
__global__ __launch_bounds__(256) void k_final(const unsigned short* __restrict__ P,
      const unsigned short* __restrict__ Rh, const unsigned short* __restrict__ Rl,
      unsigned short* __restrict__ VIh, unsigned short* __restrict__ VIl){
  int b = blockIdx.x;
  int i0 = (b>>3)*64, j0 = (b&7)*64;
  __shared__ __align__(16) unsigned short Ah[64*40], Bh[64*40], Bl[64*40];
  int t = threadIdx.x, lane = t&63, wave = t>>6;
  int wr = wave>>1, wc = wave&1;
  int lrow = lane & 15, kc = (lane>>4)*8;
  f32x4 acc[2][2];
  #pragma unroll
  for (int a = 0; a < 2; a++)
    #pragma unroll
    for (int c = 0; c < 2; c++) acc[a][c] = (f32x4){0.f,0.f,0.f,0.f};
  int r = t>>2, c8 = (t&3)*8;
  const unsigned short* pA  = P  + (size_t)(i0+r)*NDIM + c8;
  const unsigned short* pBh = Rh + (size_t)(j0+r)*NDIM + c8;
  const unsigned short* pBl = Rl + (size_t)(j0+r)*NDIM + c8;
  uint4 ra = *(const uint4*)pA, rbh = *(const uint4*)pBh, rbl = *(const uint4*)pBl;
  for (int kt = 0; kt < 16; kt++){
    *(uint4*)&Ah[r*40 + c8] = ra;
    *(uint4*)&Bh[r*40 + c8] = rbh;
    *(uint4*)&Bl[r*40 + c8] = rbl;
    __syncthreads();
    if (kt < 15){
      pA += 32; pBh += 32; pBl += 32;
      ra = *(const uint4*)pA; rbh = *(const uint4*)pBh; rbl = *(const uint4*)pBl;
    }
    short8 fa[2], fbh[2], fbl[2];
    #pragma unroll
    for (int f = 0; f < 2; f++){
      fa[f]  = *(const short8*)&Ah[(wr*32 + f*16 + lrow)*40 + kc];
      fbh[f] = *(const short8*)&Bh[(wc*32 + f*16 + lrow)*40 + kc];
      fbl[f] = *(const short8*)&Bl[(wc*32 + f*16 + lrow)*40 + kc];
    }
    #pragma unroll
    for (int fi = 0; fi < 2; fi++)
      #pragma unroll
      for (int fj = 0; fj < 2; fj++){
        acc[fi][fj] = __builtin_amdgcn_mfma_f32_16x16x32_bf16(fa[fi], fbh[fj], acc[fi][fj], 0,0,0);
        acc[fi][fj] = __builtin_amdgcn_mfma_f32_16x16x32_bf16(fa[fi], fbl[fj], acc[fi][fj], 0,0,0);
      }
    __syncthreads();
  }
  #pragma unroll
  for (int fi = 0; fi < 2; fi++)
    #pragma unroll
    for (int fj = 0; fj < 2; fj++)
      #pragma unroll
      for (int e = 0; e < 4; e++){
        int gi = i0 + wr*32 + fi*16 + (lane>>4)*4 + e;
        int gj = j0 + wc*32 + fj*16 + lrow;
        size_t o = (size_t)gi*NDIM + gj;
        float vi = bf2f(P[o]) + acc[fi][fj][e];
        unsigned short hi = f2bf(vi);
        VIh[o] = hi; VIl[o] = f2bf(vi - bf2f(hi));
      }
}

// ------- Zt[i][a] = bf16( (Xt VI^T)[i][a] ) hi/lo both sides -------
__global__ __launch_bounds__(256) void k_gemmZ(const unsigned short* __restrict__ Xth,
    const unsigned short* __restrict__ Xtl, const unsigned short* __restrict__ VIh,
    const unsigned short* __restrict__ VIl, unsigned short* __restrict__ Zt){
  __shared__ __align__(16) unsigned short Ah[64*40], Al[64*40], Bh[64*40], Bl[64*40];
  int i0 = blockIdx.x*64, j0 = blockIdx.y*64;
  int t = threadIdx.x, lane = t&63, wave = t>>6;
  int wr = wave>>1, wc = wave&1;
  int lrow = lane & 15, kc = (lane>>4)*8;
  f32x4 acc[2][2];
  #pragma unroll
  for (int a = 0; a < 2; a++)
    #pragma unroll
    for (int c = 0; c < 2; c++) acc[a][c] = (f32x4){0.f,0.f,0.f,0.f};
  int r = t>>2, c8 = (t&3)*8;
  const unsigned short* pAh = Xth + (size_t)(i0+r)*NDIM + c8;
  const unsigned short* pAl = Xtl + (size_t)(i0+r)*NDIM + c8;
  const unsigned short* pBh = VIh + (size_t)(j0+r)*NDIM + c8;
  const unsigned short* pBl = VIl + (size_t)(j0+r)*NDIM + c8;
  uint4 ra_h = *(const uint4*)pAh, ra_l = *(const uint4*)pAl;
  uint4 rb_h = *(const uint4*)pBh, rb_l = *(const uint4*)pBl;
  for (int kt = 0; kt < 16; kt++){
    *(uint4*)&Ah[r*40 + c8] = ra_h;
    *(uint4*)&Al[r*40 + c8] = ra_l;
    *(uint4*)&Bh[r*40 + c8] = rb_h;
    *(uint4*)&Bl[r*40 + c8] = rb_l;
    __syncthreads();
    if (kt < 15){
      pAh += 32; pAl += 32; pBh += 32; pBl += 32;
      ra_h = *(const uint4*)pAh; ra_l = *(const uint4*)pAl;
      rb_h = *(const uint4*)pBh; rb_l = *(const uint4*)pBl;
    }
    short8 fah[2], fal[2], fbh[2], fbl[2];
    #pragma unroll
    for (int f = 0; f < 2; f++){
      fah[f] = *(const short8*)&Ah[(wr*32 + f*16 + lrow)*40 + kc];
      fal[f] = *(const short8*)&Al[(wr*32 + f*16 + lrow)*40 + kc];
      fbh[f] = *(const short8*)&Bh[(wc*32 + f*16 + lrow)*40 + kc];
      fbl[f] = *(const short8*)&Bl[(wc*32 + f*16 + lrow)*40 + kc];
    }
    #pragma unroll
    for (int fi = 0; fi < 2; fi++)
      #pragma unroll
      for (int fj = 0; fj < 2; fj++){
        acc[fi][fj] = __builtin_amdgcn_mfma_f32_16x16x32_bf16(fah[fi], fbh[fj], acc[fi][fj], 0,0,0);
        acc[fi][fj] = __builtin_amdgcn_mfma_f32_16x16x32_bf16(fah[fi], fbl[fj], acc[fi][fj], 0,0,0);
        acc[fi][fj] = __builtin_amdgcn_mfma_f32_16x16x32_bf16(fal[fi], fbh[fj], acc[fi][fj], 0,0,0);
      }
    __syncthreads();
  }
  #pragma unroll
  for (int fi = 0; fi < 2; fi++)
    #pragma unroll
    for (int fj = 0; fj < 2; fj++)
      #pragma unroll
      for (int e = 0; e < 4; e++){
        int gi = i0 + wr*32 + fi*16 + (lane>>4)*4 + e;
        int gj = j0 + wc*32 + fj*16 + lrow;
        Zt[(size_t)gi*NDIM + gj] = f2bf(acc[fi][fj][e]);
      }
}

// ---------------- q[i] = dot(Xth[i,:], Zt[i,:]) ----------------
__global__ void k_q(const unsigned short* __restrict__ Xt, const unsigned short* __restrict__ Zt,
                    float* __restrict__ q){
  int wave = threadIdx.x >> 6, lane = threadIdx.x & 63;
  int i = blockIdx.x * 4 + wave;
  uint4 xv = *(const uint4*)(Xt + (size_t)i*NDIM + lane*8);
  uint4 zv = *(const uint4*)(Zt + (size_t)i*NDIM + lane*8);
  const unsigned short* xs = (const unsigned short*)&xv;
  const unsigned short* zs = (const unsigned short*)&zv;
  float s = 0.f;
  #pragma unroll
  for (int e = 0; e < 8; e++) s += bf2f(xs[e]) * bf2f(zs[e]);
  #pragma unroll
  for (int off = 32; off > 0; off >>= 1) s += __shfl_down(s, off, 64);
  if (lane == 0) q[i] = s;
}

// ------- G: triangular grid, BK=64, global_load_lds + XOR-swizzled LDS -------
__global__ __launch_bounds__(256) void k_G(const unsigned short* __restrict__ Xt,
        const unsigned short* __restrict__ Zt, const float* __restrict__ q,
        float* __restrict__ out){
  const int NT = NPTS/128; // 32
  int b = blockIdx.x;
  int ti = 0, rem = b;
  while (rem >= NT - ti){ rem -= NT - ti; ti++; }
  int tj = ti + rem;
  int i0 = ti*128, j0 = tj*128;

  __shared__ __align__(16) unsigned short At[128*64];
  __shared__ __align__(16) unsigned short Bt[128*64];
  int t = threadIdx.x, lane = t & 63, wave = t >> 6;
  int wr = wave >> 1, wc = wave & 1;
  f32x4 acc[4][4];
  #pragma unroll
  for (int a = 0; a < 4; a++)
    #pragma unroll
    for (int c = 0; c < 4; c++) acc[a][c] = (f32x4){0.f,0.f,0.f,0.f};

  // staging geometry: per operand 16 groups of 8 rows; wave w stages groups w*4..w*4+3
  int srow = lane >> 3;                 // row within 8-row group
  int sgk  = (lane & 7) ^ srow;         // pre-swizzled source granule (16B units)
  int lrow = lane & 15;

  for (int kb = 0; kb < NDIM; kb += 64){
    #pragma unroll
    for (int s = 0; s < 4; s++){
      int g = wave*4 + s;
      int r = g*8 + srow;
      gload16(Xt + (size_t)(i0 + r)*NDIM + kb + sgk*8, &At[g*512]);
      gload16(Zt + (size_t)(j0 + r)*NDIM + kb + sgk*8, &Bt[g*512]);
    }
    __syncthreads();
    #pragma unroll
    for (int c = 0; c < 2; c++){
      short8 af[4], bfr[4];
      int glog = c*4 + (lane>>4);
      #pragma unroll
      for (int f = 0; f < 4; f++){
        int fra = wr*64 + f*16 + lrow;
        int frb = wc*64 + f*16 + lrow;
        af[f]  = *(const short8*)&At[fra*64 + ((glog ^ (fra&7))<<3)];
        bfr[f] = *(const short8*)&Bt[frb*64 + ((glog ^ (frb&7))<<3)];
      }
      #pragma unroll
      for (int fi = 0; fi < 4; fi++)
        #pragma unroll
        for (int fj = 0; fj < 4; fj++)
          acc[fi][fj] = __builtin_amdgcn_mfma_f32_16x16x32_bf16(af[fi], bfr[fj], acc[fi][fj], 0, 0, 0);
    }
    __syncthreads();
  }
  #pragma unroll
  for (int fi = 0; fi < 4; fi++){
    #pragma unroll
    for (int fj = 0; fj < 4; fj++){
      #pragma unroll
      for (int e = 0; e < 4; e++){
        int gi = i0 + wr*64 + fi*16 + (lane >> 4)*4 + e;
        int gj = j0 + wc*64 + fj*16 + lrow;
        if (gi < gj){
          float d2 = q[gi] + q[gj] - 2.0f * acc[fi][fj][e];
          size_t idx = (size_t)gi * NPTS - ((size_t)gi*(gi+1))/2 + (size_t)(gj - gi - 1);
          out[idx] = sqrtf(fmaxf(d2, 1e-12f));
        }
      }
    }
  }
}

extern "C" void kernel_launch(void* const* d_in, const int* in_sizes, int n_in,
                              void* d_out, int out_size, void* d_ws, size_t ws_size,
                              hipStream_t stream) {
  (void)in_sizes; (void)n_in; (void)out_size; (void)ws_size;
  const float* x0 = (const float*)d_in[0];
  const float* x1 = (const float*)d_in[1];
  float* out = (float*)d_out;

  char* w = (char*)d_ws;
  float* mu     = (float*)w; w += 4096;
  float* rowsum = (float*)w; w += 4096;
  float* rinv   = (float*)w; w += 4096;
  float* q      = (float*)w; w += NPTS*4;
  float* V      = (float*)w; w += (size_t)NDIM*NDIM*4;
  unsigned short* Vh = (unsigned short*)w; w += (size_t)NDIM*NDIM*2;
  unsigned short* Vl = (unsigned short*)w; w += (size_t)NDIM*NDIM*2;
  unsigned short* Xch = (unsigned short*)w; w += (size_t)NDIM*NPTS*2;
  unsigned short* Xcl = (unsigned short*)w; w += (size_t)NDIM*NPTS*2;
  unsigned short* Xth = (unsigned short*)w; w += (size_t)NDIM*NPTS*2;
  unsigned short* Xtl = (unsigned short*)w; w += (size_t)NDIM*NPTS*2;
  // union span: 8 x 0.5MB bf16 mats + Zt(4MB) = 8MB, aliased by Vp (KSPLIT x 1MB f32)
  char* uspan = w;
  unsigned short* E0 = (unsigned short*)uspan;
  unsigned short* E1 = E0 + (size_t)NDIM*NDIM;
  unsigned short* P0 = E1 + (size_t)NDIM*NDIM;
  unsigned short* P1 = P0 + (size_t)NDIM*NDIM;
  unsigned short* Rh = P1 + (size_t)NDIM*NDIM;
  unsigned short* Rl = Rh + (size_t)NDIM*NDIM;
  unsigned short* VIh = Rl + (size_t)NDIM*NDIM;
  unsigned short* VIl = VIh + (size_t)NDIM*NDIM;
  unsigned short* Zt  = VIl + (size_t)NDIM*NDIM;
  float* Vp = (float*)uspan;  // KSPLIT * 1MB, dead after k_finV

  k_rowmean<<<dim3(512), dim3(256), 0, stream>>>(x0, x1, mu);
  k_prep<<<dim3(64,8), dim3(256), 0, stream>>>(x0, x1, mu, Xch, Xcl, Xth, Xtl);
  k_V_mfma<<<dim3(36, KSPLIT), dim3(256), 0, stream>>>(Xch, Xcl, Vp);
  k_finV<<<dim3(512), dim3(64), 0, stream>>>(Vp, V, rowsum);
  k_rinv<<<dim3(1), dim3(512), 0, stream>>>(rowsum, rinv);
  k_initEP<<<dim3(512), dim3(64), 0, stream>>>(V, rinv, E0, P0, Vh, Vl);

  unsigned short *Ec = E0, *En = E1, *Pc = P0, *Pn = P1;
  for (int it = 0; it < 7; ++it){
    k_ns<<<dim3(128), dim3(256), 0, stream>>>(Ec, Pc, En, Pn);
    unsigned short* tmp;
    tmp = Ec; Ec = En; En = tmp;
    tmp = Pc; Pc = Pn; Pn = tmp;
  }
  k_resid<<<dim3(64), dim3(256), 0, stream>>>(Vh, Vl, Pc, Rh, Rl);
  k_final<<<dim3(64), dim3(256), 0, stream>>>(Pc, Rh, Rl, VIh, VIl);
  k_gemmZ<<<dim3(64,8), dim3(256), 0, stream>>>(Xth, Xtl, VIh, VIl, Zt);
  k_q<<<dim3(1024), dim3(256), 0, stream>>>(Xth, Zt, q);
  k_G<<<dim3(528), dim3(256), 0, stream>>>(Xth, Zt, q, out);
}

// Round 4
// 192.232 us; speedup vs baseline: 3.6587x; 1.0058x over previous
//
#include <hip/hip_runtime.h>
#include <hip/hip_bf16.h>
#include <math.h>

#define NDIM 512
#define NPTS 4096
#define KSPLIT 8

typedef __attribute__((ext_vector_type(4))) float f32x4;
typedef __attribute__((ext_vector_type(8))) short short8;

__device__ __forceinline__ const float* xrow(const float* x0, const float* x1, int r){
  return (r < 256) ? (x0 + (size_t)r * NPTS) : (x1 + (size_t)(r - 256) * NPTS);
}
__device__ __forceinline__ unsigned short f2bf(float f){
  __hip_bfloat16 h = __float2bfloat16(f);
  return *reinterpret_cast<unsigned short*>(&h);
}
__device__ __forceinline__ float bf2f(unsigned short u){
  return __uint_as_float(((unsigned int)u) << 16);
}
__device__ __forceinline__ void gload16(const void* g, void* l){
  __builtin_amdgcn_global_load_lds((const __attribute__((address_space(1))) void*)g,
                                   (__attribute__((address_space(3))) void*)l, 16, 0, 0);
}

// ---------------- row means of X (512 rows x 4096) ----------------
__global__ void k_rowmean(const float* __restrict__ x0, const float* __restrict__ x1,
                          float* __restrict__ mu){
  int r = blockIdx.x;
  const float4* row4 = (const float4*)xrow(x0, x1, r);
  float s = 0.f;
  for (int c = threadIdx.x; c < NPTS/4; c += 256){
    float4 v = row4[c];
    s += v.x + v.y + v.z + v.w;
  }
  __shared__ float red[256];
  red[threadIdx.x] = s; __syncthreads();
  for (int off = 128; off > 0; off >>= 1){
    if (threadIdx.x < off) red[threadIdx.x] += red[threadIdx.x + off];
    __syncthreads();
  }
  if (threadIdx.x == 0) mu[r] = red[0] * (1.0f / NPTS);
}

// ------- prep: centered X in bf16 hi/lo, both layouts -------
__global__ __launch_bounds__(256) void k_prep(const float* __restrict__ x0, const float* __restrict__ x1,
      const float* __restrict__ mu,
      unsigned short* __restrict__ Xch, unsigned short* __restrict__ Xcl,
      unsigned short* __restrict__ Xth, unsigned short* __restrict__ Xtl){
  __shared__ float tile[64][65];
  int i0 = blockIdx.x * 64, a0 = blockIdx.y * 64;
  int t = threadIdx.x;
  int r = t >> 2, cg = (t & 3) * 16;
  const float* row = xrow(x0, x1, a0 + r);
  float m = mu[a0 + r];
  unsigned short h16[16] __attribute__((aligned(16)));
  unsigned short l16[16] __attribute__((aligned(16)));
  #pragma unroll
  for (int e = 0; e < 16; e += 4){
    float4 v = *(const float4*)(row + i0 + cg + e);
    v.x -= m; v.y -= m; v.z -= m; v.w -= m;
    tile[r][cg+e] = v.x; tile[r][cg+e+1] = v.y; tile[r][cg+e+2] = v.z; tile[r][cg+e+3] = v.w;
    h16[e]   = f2bf(v.x); l16[e]   = f2bf(v.x - bf2f(h16[e]));
    h16[e+1] = f2bf(v.y); l16[e+1] = f2bf(v.y - bf2f(h16[e+1]));
    h16[e+2] = f2bf(v.z); l16[e+2] = f2bf(v.z - bf2f(h16[e+2]));
    h16[e+3] = f2bf(v.w); l16[e+3] = f2bf(v.w - bf2f(h16[e+3]));
  }
  unsigned short* dst = Xch + (size_t)(a0+r)*NPTS + i0 + cg;
  *(uint4*)dst = *(uint4*)&h16[0]; *(uint4*)(dst+8) = *(uint4*)&h16[8];
  dst = Xcl + (size_t)(a0+r)*NPTS + i0 + cg;
  *(uint4*)dst = *(uint4*)&l16[0]; *(uint4*)(dst+8) = *(uint4*)&l16[8];
  __syncthreads();
  unsigned short th[16] __attribute__((aligned(16)));
  unsigned short tl[16] __attribute__((aligned(16)));
  #pragma unroll
  for (int e = 0; e < 16; e++){
    float v = tile[cg+e][r];
    th[e] = f2bf(v); tl[e] = f2bf(v - bf2f(th[e]));
  }
  unsigned short* d2 = Xth + (size_t)(i0 + r)*NDIM + a0 + cg;
  *(uint4*)d2 = *(uint4*)&th[0]; *(uint4*)(d2+8) = *(uint4*)&th[8];
  d2 = Xtl + (size_t)(i0 + r)*NDIM + a0 + cg;
  *(uint4*)d2 = *(uint4*)&tl[0]; *(uint4*)(d2+8) = *(uint4*)&tl[8];
}

// ------- V partials, upper-triangle tiles only, mirror-written -------
__global__ __launch_bounds__(256) void k_V_mfma(const unsigned short* __restrict__ Xch,
        const unsigned short* __restrict__ Xcl, float* __restrict__ Vp){
  int b = blockIdx.x;
  int ti = 0, rem = b;
  while (rem >= 8 - ti){ rem -= 8 - ti; ti++; }
  int tj = ti + rem;
  int i0 = ti*64, j0 = tj*64;
  int z = blockIdx.y;
  __shared__ __align__(16) unsigned short Ah[64*40], Al[64*40], Bh[64*40], Bl[64*40];
  int t = threadIdx.x, lane = t&63, wave = t>>6;
  int wr = wave>>1, wc = wave&1;
  int lrow = lane & 15, kc = (lane>>4)*8;
  f32x4 acc[2][2];
  #pragma unroll
  for (int a = 0; a < 2; a++)
    #pragma unroll
    for (int c = 0; c < 2; c++) acc[a][c] = (f32x4){0.f,0.f,0.f,0.f};
  int r = t>>2, c8 = (t&3)*8;
  size_t kbase = (size_t)z * (NPTS/KSPLIT);
  const unsigned short* pAh = Xch + (size_t)(i0+r)*NPTS + kbase + c8;
  const unsigned short* pAl = Xcl + (size_t)(i0+r)*NPTS + kbase + c8;
  const unsigned short* pBh = Xch + (size_t)(j0+r)*NPTS + kbase + c8;
  const unsigned short* pBl = Xcl + (size_t)(j0+r)*NPTS + kbase + c8;
  uint4 ra_h = *(const uint4*)pAh, ra_l = *(const uint4*)pAl;
  uint4 rb_h = *(const uint4*)pBh, rb_l = *(const uint4*)pBl;
  const int NK = (NPTS/KSPLIT)/32;
  for (int kt = 0; kt < NK; kt++){
    *(uint4*)&Ah[r*40 + c8] = ra_h;
    *(uint4*)&Al[r*40 + c8] = ra_l;
    *(uint4*)&Bh[r*40 + c8] = rb_h;
    *(uint4*)&Bl[r*40 + c8] = rb_l;
    __syncthreads();
    if (kt+1 < NK){
      pAh += 32; pAl += 32; pBh += 32; pBl += 32;
      ra_h = *(const uint4*)pAh; ra_l = *(const uint4*)pAl;
      rb_h = *(const uint4*)pBh; rb_l = *(const uint4*)pBl;
    }
    short8 fah[2], fal[2], fbh[2], fbl[2];
    #pragma unroll
    for (int f = 0; f < 2; f++){
      fah[f] = *(const short8*)&Ah[(wr*32 + f*16 + lrow)*40 + kc];
      fal[f] = *(const short8*)&Al[(wr*32 + f*16 + lrow)*40 + kc];
      fbh[f] = *(const short8*)&Bh[(wc*32 + f*16 + lrow)*40 + kc];
      fbl[f] = *(const short8*)&Bl[(wc*32 + f*16 + lrow)*40 + kc];
    }
    #pragma unroll
    for (int fi = 0; fi < 2; fi++)
      #pragma unroll
      for (int fj = 0; fj < 2; fj++){
        acc[fi][fj] = __builtin_amdgcn_mfma_f32_16x16x32_bf16(fah[fi], fbh[fj], acc[fi][fj], 0,0,0);
        acc[fi][fj] = __builtin_amdgcn_mfma_f32_16x16x32_bf16(fah[fi], fbl[fj], acc[fi][fj], 0,0,0);
        acc[fi][fj] = __builtin_amdgcn_mfma_f32_16x16x32_bf16(fal[fi], fbh[fj], acc[fi][fj], 0,0,0);
      }
    __syncthreads();
  }
  float* dst = Vp + (size_t)z*NDIM*NDIM;
  #pragma unroll
  for (int fi = 0; fi < 2; fi++)
    #pragma unroll
    for (int fj = 0; fj < 2; fj++)
      #pragma unroll
      for (int e = 0; e < 4; e++){
        int gi = i0 + wr*32 + fi*16 + (lane>>4)*4 + e;
        int gj = j0 + wc*32 + fj*16 + lrow;
        dst[(size_t)gi*NDIM + gj] = acc[fi][fj][e];
        if (ti != tj) dst[(size_t)gj*NDIM + gi] = acc[fi][fj][e];
      }
}

// ------- finV: V = sum_z Vp[z]/4095 ; rowsum = sum_j |V[r][j]| -------
__global__ void k_finV(const float* __restrict__ Vp, float* __restrict__ V,
                       float* __restrict__ rowsum){
  int r = blockIdx.x, lane = threadIdx.x; // 64 threads
  const size_t S = (size_t)NDIM*NDIM;
  float a[8] = {0,0,0,0,0,0,0,0};
  #pragma unroll
  for (int z = 0; z < KSPLIT; z++){
    const float* p = Vp + z*S + (size_t)r*NDIM + lane*8;
    float4 u = *(const float4*)p;
    float4 v = *(const float4*)(p+4);
    a[0]+=u.x; a[1]+=u.y; a[2]+=u.z; a[3]+=u.w;
    a[4]+=v.x; a[5]+=v.y; a[6]+=v.z; a[7]+=v.w;
  }
  const float s = 1.0f/4095.0f;
  float asum = 0.f;
  #pragma unroll
  for (int e = 0; e < 8; e++){ a[e] *= s; asum += fabsf(a[e]); }
  float* dst = V + (size_t)r*NDIM + lane*8;
  *(float4*)dst = (float4){a[0],a[1],a[2],a[3]};
  *(float4*)(dst+4) = (float4){a[4],a[5],a[6],a[7]};
  #pragma unroll
  for (int off = 32; off > 0; off >>= 1) asum += __shfl_down(asum, off, 64);
  if (lane == 0) rowsum[r] = asum;
}

// ------- init: E0 = I - cV, P0 = cI (bf16); Vh/Vl split; c from rowsum max in-kernel -------
__global__ void k_initEP(const float* __restrict__ V, const float* __restrict__ rowsum,
      unsigned short* __restrict__ E0, unsigned short* __restrict__ P0,
      unsigned short* __restrict__ Vh, unsigned short* __restrict__ Vl){
  int r = blockIdx.x, lane = threadIdx.x; // 64 threads
  float m = 0.f;
  #pragma unroll
  for (int e = 0; e < 8; e++) m = fmaxf(m, rowsum[lane*8 + e]);
  #pragma unroll
  for (int off = 32; off > 0; off >>= 1) m = fmaxf(m, __shfl_xor(m, off, 64));
  float c = 1.0f / m;
  const float* src = V + (size_t)r*NDIM + lane*8;
  unsigned short vh[8] __attribute__((aligned(16))), vl[8] __attribute__((aligned(16)));
  unsigned short e8[8] __attribute__((aligned(16))), p8[8] __attribute__((aligned(16)));
  #pragma unroll
  for (int e = 0; e < 8; e++){
    float v = src[e];
    vh[e] = f2bf(v); vl[e] = f2bf(v - bf2f(vh[e]));
    int col = lane*8 + e;
    float ev = ((col==r)?1.f:0.f) - c*v;
    e8[e] = f2bf(ev);
    p8[e] = f2bf((col==r)?c:0.f);
  }
  size_t o = (size_t)r*NDIM + lane*8;
  *(uint4*)&Vh[o] = *(uint4*)vh; *(uint4*)&Vl[o] = *(uint4*)vl;
  *(uint4*)&E0[o] = *(uint4*)e8; *(uint4*)&P0[o] = *(uint4*)p8;
}

// ------- fused NS iteration: blocks 0-63: En = E*E ; 64-127: Pn = P + P*E -------
__global__ __launch_bounds__(256) void k_ns(const unsigned short* __restrict__ E,
      const unsigned short* __restrict__ P,
      unsigned short* __restrict__ En, unsigned short* __restrict__ Pn){
  int b = blockIdx.x;
  int half = b >> 6, tile = b & 63;
  int i0 = (tile>>3)*64, j0 = (tile&7)*64;
  const unsigned short* Asrc = half ? P : E;
  __shared__ __align__(16) unsigned short Ah[64*40], Bh[64*40];
  int t = threadIdx.x, lane = t&63, wave = t>>6;
  int wr = wave>>1, wc = wave&1;
  int lrow = lane & 15, kc = (lane>>4)*8;
  f32x4 acc[2][2];
  #pragma unroll
  for (int a = 0; a < 2; a++)
    #pragma unroll
    for (int c = 0; c < 2; c++) acc[a][c] = (f32x4){0.f,0.f,0.f,0.f};
  int r = t>>2, c8 = (t&3)*8;
  const unsigned short* pA = Asrc + (size_t)(i0+r)*NDIM + c8;
  const unsigned short* pB = E + (size_t)(j0+r)*NDIM + c8;
  uint4 ra = *(const uint4*)pA, rb = *(const uint4*)pB;
  for (int kt = 0; kt < 16; kt++){
    *(uint4*)&Ah[r*40 + c8] = ra;
    *(uint4*)&Bh[r*40 + c8] = rb;
    __syncthreads();
    if (kt < 15){
      pA += 32; pB += 32;
      ra = *(const uint4*)pA; rb = *(const uint4*)pB;
    }
    short8 fa[2], fb[2];
    #pragma unroll
    for (int f = 0; f < 2; f++){
      fa[f] = *(const short8*)&Ah[(wr*32 + f*16 + lrow)*40 + kc];
      fb[f] = *(const short8*)&Bh[(wc*32 + f*16 + lrow)*40 + kc];
    }
    #pragma unroll
    for (int fi = 0; fi < 2; fi++)
      #pragma unroll
      for (int fj = 0; fj < 2; fj++)
        acc[fi][fj] = __builtin_amdgcn_mfma_f32_16x16x32_bf16(fa[fi], fb[fj], acc[fi][fj], 0,0,0);
    __syncthreads();
  }
  #pragma unroll
  for (int fi = 0; fi < 2; fi++)
    #pragma unroll
    for (int fj = 0; fj < 2; fj++)
      #pragma unroll
      for (int e = 0; e < 4; e++){
        int gi = i0 + wr*32 + fi*16 + (lane>>4)*4 + e;
        int gj = j0 + wc*32 + fj*16 + lrow;
        size_t o = (size_t)gi*NDIM + gj;
        if (half) Pn[o] = f2bf(bf2f(P[o]) + acc[fi][fj][e]);
        else      En[o] = f2bf(acc[fi][fj][e]);
      }
}

// ------- resid: R = I - (Vh+Vl)*P, stored TRANSPOSED as hi/lo bf16 -------
__global__ __launch_bounds__(256) void k_resid(const unsigned short* __restrict__ Vh,
      const unsigned short* __restrict__ Vl, const unsigned short* __restrict__ P,
      unsigned short* __restrict__ Rh, unsigned short* __restrict__ Rl){
  int b = blockIdx.x;
  int i0 = (b>>3)*64, j0 = (b&7)*64;
  __shared__ __align__(16) unsigned short Ah[64*40], Al[64*40], Bh[64*40];
  int t = threadIdx.x, lane = t&63, wave = t>>6;
  int wr = wave>>1, wc = wave&1;
  int lrow = lane & 15, kc = (lane>>4)*8;
  f32x4 acc[2][2];
  #pragma unroll
  for (int a = 0; a < 2; a++)
    #pragma unroll
    for (int c = 0; c < 2; c++) acc[a][c] = (f32x4){0.f,0.f,0.f,0.f};
  int r = t>>2, c8 = (t&3)*8;
  const unsigned short* pAh = Vh + (size_t)(i0+r)*NDIM + c8;
  const unsigned short* pAl = Vl + (size_t)(i0+r)*NDIM + c8;
  const unsigned short* pB  = P  + (size_t)(j0+r)*NDIM + c8;
  uint4 rah = *(const uint4*)pAh, ral = *(const uint4*)pAl, rb = *(const uint4*)pB;
  for (int kt = 0; kt < 16; kt++){
    *(uint4*)&Ah[r*40 + c8] = rah;
    *(uint4*)&Al[r*40 + c8] = ral;
    *(uint4*)&Bh[r*40 + c8] = rb;
    __syncthreads();
    if (kt < 15){
      pAh += 32; pAl += 32; pB += 32;
      rah = *(const uint4*)pAh; ral = *(const uint4*)pAl; rb = *(const uint4*)pB;
    }
    short8 fah[2], fal[2], fb[2];
    #pragma unroll
    for (int f = 0; f < 2; f++){
      fah[f] = *(const short8*)&Ah[(wr*32 + f*16 + lrow)*40 + kc];
      fal[f] = *(const short8*)&Al[(wr*32 + f*16 + lrow)*40 + kc];
      fb[f]  = *(const short8*)&Bh[(wc*32 + f*16 + lrow)*40 + kc];
    }
    #pragma unroll
    for (int fi = 0; fi < 2; fi++)
      #pragma unroll
      for (int fj = 0; fj < 2; fj++){
        acc[fi][fj] = __builtin_amdgcn_mfma_f32_16x16x32_bf16(fah[fi], fb[fj], acc[fi][fj], 0,0,0);
        acc[fi][fj] = __builtin_amdgcn_mfma_f32_16x16x32_bf16(fal[fi], fb[fj], acc[fi][fj], 0,0,0);
      }
    __syncthreads();
  }
  #pragma unroll
  for (int fi = 0; fi < 2; fi++)
    #pragma unroll
    for (int fj = 0; fj < 2; fj++)
      #pragma unroll
      for (int e = 0; e < 4; e++){
        int gi = i0 + wr*32 + fi*16 + (lane>>4)*4 + e;
        int gj = j0 + wc*32 + fj*16 + lrow;
        float rv = ((gi==gj)?1.f:0.f) - acc[fi][fj][e];
        unsigned short hi = f2bf(rv);
        size_t o = (size_t)gj*NDIM + gi;   // transposed store
        Rh[o] = hi; Rl[o] = f2bf(rv - bf2f(hi));
      }
}

// ------- final: VI = P + P*R -> VIh/VIl -------
__global__ __launch_bounds__(256) void k_final(const unsigned short* __restrict__ P,
      const unsigned short* __restrict__ Rh, const unsigned short* __restrict__ Rl,
      unsigned short* __restrict__ VIh, unsigned short* __restrict__ VIl){
  int b = blockIdx.x;
  int i0 = (b>>3)*64, j0 = (b&7)*64;
  __shared__ __align__(16) unsigned short Ah[64*40], Bh[64*40], Bl[64*40];
  int t = threadIdx.x, lane = t&63, wave = t>>6;
  int wr = wave>>1, wc = wave&1;
  int lrow = lane & 15, kc = (lane>>4)*8;
  f32x4 acc[2][2];
  #pragma unroll
  for (int a = 0; a < 2; a++)
    #pragma unroll
    for (int c = 0; c < 2; c++) acc[a][c] = (f32x4){0.f,0.f,0.f,0.f};
  int r = t>>2, c8 = (t&3)*8;
  const unsigned short* pA  = P  + (size_t)(i0+r)*NDIM + c8;
  const unsigned short* pBh = Rh + (size_t)(j0+r)*NDIM + c8;
  const unsigned short* pBl = Rl + (size_t)(j0+r)*NDIM + c8;
  uint4 ra = *(const uint4*)pA, rbh = *(const uint4*)pBh, rbl = *(const uint4*)pBl;
  for (int kt = 0; kt < 16; kt++){
    *(uint4*)&Ah[r*40 + c8] = ra;
    *(uint4*)&Bh[r*40 + c8] = rbh;
    *(uint4*)&Bl[r*40 + c8] = rbl;
    __syncthreads();
    if (kt < 15){
      pA += 32; pBh += 32; pBl += 32;
      ra = *(const uint4*)pA; rbh = *(const uint4*)pBh; rbl = *(const uint4*)pBl;
    }
    short8 fa[2], fbh[2], fbl[2];
    #pragma unroll
    for (int f = 0; f < 2; f++){
      fa[f]  = *(const short8*)&Ah[(wr*32 + f*16 + lrow)*40 + kc];
      fbh[f] = *(const short8*)&Bh[(wc*32 + f*16 + lrow)*40 + kc];
      fbl[f] = *(const short8*)&Bl[(wc*32 + f*16 + lrow)*40 + kc];
    }
    #pragma unroll
    for (int fi = 0; fi < 2; fi++)
      #pragma unroll
      for (int fj = 0; fj < 2; fj++){
        acc[fi][fj] = __builtin_amdgcn_mfma_f32_16x16x32_bf16(fa[fi], fbh[fj], acc[fi][fj], 0,0,0);
        acc[fi][fj] = __builtin_amdgcn_mfma_f32_16x16x32_bf16(fa[fi], fbl[fj], acc[fi][fj], 0,0,0);
      }
    __syncthreads();
  }
  #pragma unroll
  for (int fi = 0; fi < 2; fi++)
    #pragma unroll
    for (int fj = 0; fj < 2; fj++)
      #pragma unroll
      for (int e = 0; e < 4; e++){
        int gi = i0 + wr*32 + fi*16 + (lane>>4)*4 + e;
        int gj = j0 + wc*32 + fj*16 + lrow;
        size_t o = (size_t)gi*NDIM + gj;
        float vi = bf2f(P[o]) + acc[fi][fj][e];
        unsigned short hi = f2bf(vi);
        VIh[o] = hi; VIl[o] = f2bf(vi - bf2f(hi));
      }
}

// ------- Zt[i][a] = bf16( (Xt VI^T)[i][a] ) hi/lo both sides -------
__global__ __launch_bounds__(256) void k_gemmZ(const unsigned short* __restrict__ Xth,
    const unsigned short* __restrict__ Xtl, const unsigned short* __restrict__ VIh,
    const unsigned short* __restrict__ VIl, unsigned short* __restrict__ Zt){
  __shared__ __align__(16) unsigned short Ah[64*40], Al[64*40], Bh[64*40], Bl[64*40];
  int i0 = blockIdx.x*64, j0 = blockIdx.y*64;
  int t = threadIdx.x, lane = t&63, wave = t>>6;
  int wr = wave>>1, wc = wave&1;
  int lrow = lane & 15, kc = (lane>>4)*8;
  f32x4 acc[2][2];
  #pragma unroll
  for (int a = 0; a < 2; a++)
    #pragma unroll
    for (int c = 0; c < 2; c++) acc[a][c] = (f32x4){0.f,0.f,0.f,0.f};
  int r = t>>2, c8 = (t&3)*8;
  const unsigned short* pAh = Xth + (size_t)(i0+r)*NDIM + c8;
  const unsigned short* pAl = Xtl + (size_t)(i0+r)*NDIM + c8;
  const unsigned short* pBh = VIh + (size_t)(j0+r)*NDIM + c8;
  const unsigned short* pBl = VIl + (size_t)(j0+r)*NDIM + c8;
  uint4 ra_h = *(const uint4*)pAh, ra_l = *(const uint4*)pAl;
  uint4 rb_h = *(const uint4*)pBh, rb_l = *(const uint4*)pBl;
  for (int kt = 0; kt < 16; kt++){
    *(uint4*)&Ah[r*40 + c8] = ra_h;
    *(uint4*)&Al[r*40 + c8] = ra_l;
    *(uint4*)&Bh[r*40 + c8] = rb_h;
    *(uint4*)&Bl[r*40 + c8] = rb_l;
    __syncthreads();
    if (kt < 15){
      pAh += 32; pAl += 32; pBh += 32; pBl += 32;
      ra_h = *(const uint4*)pAh; ra_l = *(const uint4*)pAl;
      rb_h = *(const uint4*)pBh; rb_l = *(const uint4*)pBl;
    }
    short8 fah[2], fal[2], fbh[2], fbl[2];
    #pragma unroll
    for (int f = 0; f < 2; f++){
      fah[f] = *(const short8*)&Ah[(wr*32 + f*16 + lrow)*40 + kc];
      fal[f] = *(const short8*)&Al[(wr*32 + f*16 + lrow)*40 + kc];
      fbh[f] = *(const short8*)&Bh[(wc*32 + f*16 + lrow)*40 + kc];
      fbl[f] = *(const short8*)&Bl[(wc*32 + f*16 + lrow)*40 + kc];
    }
    #pragma unroll
    for (int fi = 0; fi < 2; fi++)
      #pragma unroll
      for (int fj = 0; fj < 2; fj++){
        acc[fi][fj] = __builtin_amdgcn_mfma_f32_16x16x32_bf16(fah[fi], fbh[fj], acc[fi][fj], 0,0,0);
        acc[fi][fj] = __builtin_amdgcn_mfma_f32_16x16x32_bf16(fah[fi], fbl[fj], acc[fi][fj], 0,0,0);
        acc[fi][fj] = __builtin_amdgcn_mfma_f32_16x16x32_bf16(fal[fi], fbh[fj], acc[fi][fj], 0,0,0);
      }
    __syncthreads();
  }
  #pragma unroll
  for (int fi = 0; fi < 2; fi++)
    #pragma unroll
    for (int fj = 0; fj < 2; fj++)
      #pragma unroll
      for (int e = 0; e < 4; e++){
        int gi = i0 + wr*32 + fi*16 + (lane>>4)*4 + e;
        int gj = j0 + wc*32 + fj*16 + lrow;
        Zt[(size_t)gi*NDIM + gj] = f2bf(acc[fi][fj][e]);
      }
}

// ---------------- q[i] = dot(Xth[i,:], Zt[i,:]) ----------------
__global__ void k_q(const unsigned short* __restrict__ Xt, const unsigned short* __restrict__ Zt,
                    float* __restrict__ q){
  int wave = threadIdx.x >> 6, lane = threadIdx.x & 63;
  int i = blockIdx.x * 4 + wave;
  uint4 xv = *(const uint4*)(Xt + (size_t)i*NDIM + lane*8);
  uint4 zv = *(const uint4*)(Zt + (size_t)i*NDIM + lane*8);
  const unsigned short* xs = (const unsigned short*)&xv;
  const unsigned short* zs = (const unsigned short*)&zv;
  float s = 0.f;
  #pragma unroll
  for (int e = 0; e < 8; e++) s += bf2f(xs[e]) * bf2f(zs[e]);
  #pragma unroll
  for (int off = 32; off > 0; off >>= 1) s += __shfl_down(s, off, 64);
  if (lane == 0) q[i] = s;
}

// ------- G: triangular grid, BK=64, DOUBLE-BUFFERED global_load_lds + XOR swizzle -------
__global__ __launch_bounds__(256) void k_G(const unsigned short* __restrict__ Xt,
        const unsigned short* __restrict__ Zt, const float* __restrict__ q,
        float* __restrict__ out){
  const int NT = NPTS/128; // 32
  int b = blockIdx.x;
  int ti = 0, rem = b;
  while (rem >= NT - ti){ rem -= NT - ti; ti++; }
  int tj = ti + rem;
  int i0 = ti*128, j0 = tj*128;

  __shared__ __align__(16) unsigned short At[2][128*64];
  __shared__ __align__(16) unsigned short Bt[2][128*64];
  int t = threadIdx.x, lane = t & 63, wave = t >> 6;
  int wr = wave >> 1, wc = wave & 1;
  f32x4 acc[4][4];
  #pragma unroll
  for (int a = 0; a < 4; a++)
    #pragma unroll
    for (int c = 0; c < 4; c++) acc[a][c] = (f32x4){0.f,0.f,0.f,0.f};

  // staging geometry: per operand 16 groups of 8 rows; wave w stages groups w*4..w*4+3
  int srow = lane >> 3;                 // row within 8-row group
  int sgk  = (lane & 7) ^ srow;         // pre-swizzled source granule (16B units)
  int lrow = lane & 15;

  // prologue: stage k-tile 0 into buffer 0
  #pragma unroll
  for (int s = 0; s < 4; s++){
    int g = wave*4 + s;
    int r = g*8 + srow;
    gload16(Xt + (size_t)(i0 + r)*NDIM + 0 + sgk*8, &At[0][g*512]);
    gload16(Zt + (size_t)(j0 + r)*NDIM + 0 + sgk*8, &Bt[0][g*512]);
  }
  __syncthreads();   // drains vmcnt(0): buffer 0 ready

  int cur = 0;
  for (int kt = 0; kt < 8; kt++){
    // issue next tile's stage into the other buffer (overlaps with compute below)
    if (kt < 7){
      int kb = (kt+1)*64;
      #pragma unroll
      for (int s = 0; s < 4; s++){
        int g = wave*4 + s;
        int r = g*8 + srow;
        gload16(Xt + (size_t)(i0 + r)*NDIM + kb + sgk*8, &At[cur^1][g*512]);
        gload16(Zt + (size_t)(j0 + r)*NDIM + kb + sgk*8, &Bt[cur^1][g*512]);
      }
    }
    // compute from current buffer
    #pragma unroll
    for (int c = 0; c < 2; c++){
      short8 af[4], bfr[4];
      int glog = c*4 + (lane>>4);
      #pragma unroll
      for (int f = 0; f < 4; f++){
        int fra = wr*64 + f*16 + lrow;
        int frb = wc*64 + f*16 + lrow;
        af[f]  = *(const short8*)&At[cur][fra*64 + ((glog ^ (fra&7))<<3)];
        bfr[f] = *(const short8*)&Bt[cur][frb*64 + ((glog ^ (frb&7))<<3)];
      }
      #pragma unroll
      for (int fi = 0; fi < 4; fi++)
        #pragma unroll
        for (int fj = 0; fj < 4; fj++)
          acc[fi][fj] = __builtin_amdgcn_mfma_f32_16x16x32_bf16(af[fi], bfr[fj], acc[fi][fj], 0, 0, 0);
    }
    __syncthreads();  // drains vmcnt: next buffer ready; also protects buffer reuse
    cur ^= 1;
  }
  #pragma unroll
  for (int fi = 0; fi < 4; fi++){
    #pragma unroll
    for (int fj = 0; fj < 4; fj++){
      #pragma unroll
      for (int e = 0; e < 4; e++){
        int gi = i0 + wr*64 + fi*16 + (lane >> 4)*4 + e;
        int gj = j0 + wc*64 + fj*16 + lrow;
        if (gi < gj){
          float d2 = q[gi] + q[gj] - 2.0f * acc[fi][fj][e];
          size_t idx = (size_t)gi * NPTS - ((size_t)gi*(gi+1))/2 + (size_t)(gj - gi - 1);
          out[idx] = sqrtf(fmaxf(d2, 1e-12f));
        }
      }
    }
  }
}

extern "C" void kernel_launch(void* const* d_in, const int* in_sizes, int n_in,
                              void* d_out, int out_size, void* d_ws, size_t ws_size,
                              hipStream_t stream) {
  (void)in_sizes; (void)n_in; (void)out_size; (void)ws_size;
  const float* x0 = (const float*)d_in[0];
  const float* x1 = (const float*)d_in[1];
  float* out = (float*)d_out;

  char* w = (char*)d_ws;
  float* mu     = (float*)w; w += 4096;
  float* rowsum = (float*)w; w += 4096;
  float* q      = (float*)w; w += NPTS*4;
  float* V      = (float*)w; w += (size_t)NDIM*NDIM*4;
  unsigned short* Vh = (unsigned short*)w; w += (size_t)NDIM*NDIM*2;
  unsigned short* Vl = (unsigned short*)w; w += (size_t)NDIM*NDIM*2;
  unsigned short* Xch = (unsigned short*)w; w += (size_t)NDIM*NPTS*2;
  unsigned short* Xcl = (unsigned short*)w; w += (size_t)NDIM*NPTS*2;
  unsigned short* Xth = (unsigned short*)w; w += (size_t)NDIM*NPTS*2;
  unsigned short* Xtl = (unsigned short*)w; w += (size_t)NDIM*NPTS*2;
  // union span: 8 x 0.5MB bf16 mats + Zt(4MB) = 8MB, aliased by Vp (KSPLIT x 1MB f32)
  char* uspan = w;
  unsigned short* E0 = (unsigned short*)uspan;
  unsigned short* E1 = E0 + (size_t)NDIM*NDIM;
  unsigned short* P0 = E1 + (size_t)NDIM*NDIM;
  unsigned short* P1 = P0 + (size_t)NDIM*NDIM;
  unsigned short* Rh = P1 + (size_t)NDIM*NDIM;
  unsigned short* Rl = Rh + (size_t)NDIM*NDIM;
  unsigned short* VIh = Rl + (size_t)NDIM*NDIM;
  unsigned short* VIl = VIh + (size_t)NDIM*NDIM;
  unsigned short* Zt  = VIl + (size_t)NDIM*NDIM;
  float* Vp = (float*)uspan;  // KSPLIT * 1MB, dead after k_finV

  k_rowmean<<<dim3(512), dim3(256), 0, stream>>>(x0, x1, mu);
  k_prep<<<dim3(64,8), dim3(256), 0, stream>>>(x0, x1, mu, Xch, Xcl, Xth, Xtl);
  k_V_mfma<<<dim3(36, KSPLIT), dim3(256), 0, stream>>>(Xch, Xcl, Vp);
  k_finV<<<dim3(512), dim3(64), 0, stream>>>(Vp, V, rowsum);
  k_initEP<<<dim3(512), dim3(64), 0, stream>>>(V, rowsum, E0, P0, Vh, Vl);

  unsigned short *Ec = E0, *En = E1, *Pc = P0, *Pn = P1;
  for (int it = 0; it < 7; ++it){
    k_ns<<<dim3(128), dim3(256), 0, stream>>>(Ec, Pc, En, Pn);
    unsigned short* tmp;
    tmp = Ec; Ec = En; En = tmp;
    tmp = Pc; Pc = Pn; Pn = tmp;
  }
  k_resid<<<dim3(64), dim3(256), 0, stream>>>(Vh, Vl, Pc, Rh, Rl);
  k_final<<<dim3(64), dim3(256), 0, stream>>>(Pc, Rh, Rl, VIh, VIl);
  k_gemmZ<<<dim3(64,8), dim3(256), 0, stream>>>(Xth, Xtl, VIh, VIl, Zt);
  k_q<<<dim3(1024), dim3(256), 0, stream>>>(Xth, Zt, q);
  k_G<<<dim3(528), dim3(256), 0, stream>>>(Xth, Zt, q, out);
}